// Round 4
// baseline (476.796 us; speedup 1.0000x reference)
//
#include <hip/hip_runtime.h>
#include <hip/hip_bf16.h>

typedef _Float16 h16;
typedef _Float16 h16x8 __attribute__((ext_vector_type(8)));
typedef float f32x4 __attribute__((ext_vector_type(4)));

#define DEVI static __device__ __forceinline__

constexpr int NN = 2048;     // sequence length
constexpr int DIM = 512;
constexpr int NH = 8;
constexpr int DH = 64;
constexpr int BH = 16;       // B * H
constexpr float FSCALE = 0.125f;  // DH^-0.5

DEVI f32x4 mfma16(h16x8 a, h16x8 b, f32x4 c) {
  return __builtin_amdgcn_mfma_f32_16x16x32_f16(a, b, c, 0, 0, 0);
}

DEVI void glds16(const void* g, void* l) {
  __builtin_amdgcn_global_load_lds(
      (const __attribute__((address_space(1))) unsigned int*)g,
      (__attribute__((address_space(3))) unsigned int*)l, 16, 0, 0);
}

DEVI void tri_decode(int p, int& a, int& b) {
  a = (int)((sqrtf(8.f * p + 1.f) - 1.f) * 0.5f);
  while ((a + 1) * (a + 2) / 2 <= p) ++a;
  while (a * (a + 1) / 2 > p) --a;
  b = p - a * (a + 1) / 2;
}

// ---------------- pack kernels ----------------

__global__ __launch_bounds__(256) void k_pack_x(const float* __restrict__ x, h16* __restrict__ xh) {
  int i = (blockIdx.x * 256 + threadIdx.x) * 4;
  float4 v = *(const float4*)(x + i);
  union { h16 h[4]; uint2 u; } pk;
  pk.h[0] = (h16)v.x; pk.h[1] = (h16)v.y; pk.h[2] = (h16)v.z; pk.h[3] = (h16)v.w;
  *(uint2*)(xh + i) = pk.u;
}

struct WPtrs { const float* w[7]; };

// transpose+cast each 512x512 weight: wt[o][k] = W[k][o]
__global__ __launch_bounds__(256) void k_pack_w(WPtrs wp, h16* __restrict__ wt) {
  const float* W = wp.w[blockIdx.z];
  h16* out = wt + (size_t)blockIdx.z * DIM * DIM;
  __shared__ h16 t[64][65];
  int k0 = blockIdx.x * 64, o0 = blockIdx.y * 64;
  int c = threadIdx.x & 63, r4 = threadIdx.x >> 6;
#pragma unroll
  for (int rr = 0; rr < 64; rr += 4) {
    int r = rr + r4;
    t[r][c] = (h16)W[(size_t)(k0 + r) * DIM + o0 + c];
  }
  __syncthreads();
#pragma unroll
  for (int rr = 0; rr < 64; rr += 4) {
    int r = rr + r4;
    out[(size_t)(o0 + r) * DIM + k0 + c] = t[c][r];
  }
}

// ---------------- fused QKV projection ----------------
__global__ __launch_bounds__(256) void k_proj(const h16* __restrict__ xh, const h16* __restrict__ wt,
                                              h16* __restrict__ qkv, h16* __restrict__ vcT) {
  __shared__ h16 pool[128 * 136];
  h16* Al = pool;
  h16* Bl = pool + 128 * 64;
  int m0 = blockIdx.x * 128, o0 = blockIdx.y * 128;
  int lane = threadIdx.x & 63, wv = threadIdx.x >> 6;
  int wy = wv >> 1, wx = wv & 1;
  int srow = 32 * wv;
  int lr = lane >> 3, lc = 8 * (lane & 7);
  f32x4 acc[4][4] = {};
  for (int ks0 = 0; ks0 < DIM; ks0 += 64) {
#pragma unroll
    for (int inst = 0; inst < 4; inst++) {
      int r = srow + 8 * inst;
      glds16(xh + (size_t)(m0 + r + lr) * DIM + ks0 + lc, Al + r * 64);
      glds16(wt + (size_t)(o0 + r + lr) * DIM + ks0 + lc, Bl + r * 64);
    }
    __syncthreads();
#pragma unroll
    for (int ks = 0; ks < 2; ks++) {
      h16x8 af[4], bfv[4];
      int co = 32 * ks + 8 * (lane >> 4);
#pragma unroll
      for (int i = 0; i < 4; i++) af[i] = *(const h16x8*)(Al + (64 * wy + 16 * i + (lane & 15)) * 64 + co);
#pragma unroll
      for (int j = 0; j < 4; j++) bfv[j] = *(const h16x8*)(Bl + (64 * wx + 16 * j + (lane & 15)) * 64 + co);
#pragma unroll
      for (int i = 0; i < 4; i++)
#pragma unroll
        for (int j = 0; j < 4; j++) acc[i][j] = mfma16(af[i], bfv[j], acc[i][j]);
    }
    __syncthreads();
  }
  int widx = o0 >> 9;
  float scl = (widx == 0 || widx == 3) ? FSCALE : 1.0f;
  h16 (*Clds)[136] = (h16(*)[136])pool;
#pragma unroll
  for (int i = 0; i < 4; i++)
#pragma unroll
    for (int j = 0; j < 4; j++)
#pragma unroll
      for (int r = 0; r < 4; r++) {
        int rloc = 64 * wy + 16 * i + (lane >> 4) * 4 + r;
        int cloc = 64 * wx + 16 * j + (lane & 15);
        Clds[rloc][cloc] = (h16)(acc[i][j][r] * scl);
      }
  __syncthreads();
  int t = threadIdx.x;
  {
    int rloc = t >> 1, half = t & 1;
    int gi = m0 + rloc;
    int b = gi >> 11, n = gi & 2047;
    int og = o0 + 64 * half;
    int h = (og >> 6) & 7;
    h16* dst = qkv + (((size_t)widx * BH + b * NH + h) * NN + n) * DH;
#pragma unroll
    for (int e = 0; e < 8; e++)
      *(h16x8*)(dst + 8 * e) = *(const h16x8*)&Clds[rloc][64 * half + 8 * e];
  }
  if (widx == 5) {
    int c = t & 127, rq = t >> 7;
    int og = o0 + c;
    int h = (og >> 6) & 7, d = og & 63;
    int b = m0 >> 11, nb = (m0 & 2047) + rq * 64;
    h16* dst = vcT + ((size_t)(b * NH + h) * DH + d) * NN + nb;
#pragma unroll
    for (int g = 0; g < 8; g++) {
      h16x8 w;
#pragma unroll
      for (int e = 0; e < 8; e++) w[e] = Clds[rq * 64 + 8 * g + e][c];
      *(h16x8*)(dst + 8 * g) = w;
    }
  }
}

// ---------------- term1 & sigmoid matrices ----------------
// term[i][j] = (Qc_s[i].Vu[j]) * [j<=i]; sig[k][j] = sigmoid(Qu_s[k].Ku[j]) * [j>k]
// pidx < 136: normal triangular pairs. 136..143: (2m, 2m+1) both matrices.
// 144..151: (2m+1, 2m) sig only (term already covered by normal pairs).
__global__ __launch_bounds__(256) void k_termsig(const h16* __restrict__ qkv,
                                                 h16* __restrict__ term, h16* __restrict__ sig, int bh0) {
  int pidx = blockIdx.x;
  bool is_sig = blockIdx.y != 0;
  int lz = blockIdx.z, bh = bh0 + lz;
  int rt, jt;
  if (pidx >= 144) {
    if (!is_sig) return;
    int mm = pidx - 144;
    rt = 2 * mm + 1; jt = 2 * mm;
  } else if (pidx >= 136) {
    int mm = pidx - 136;
    rt = 2 * mm; jt = 2 * mm + 1;
  } else {
    int a, bq;
    tri_decode(pidx, a, bq);
    rt = is_sig ? bq : a;
    jt = is_sig ? a : bq;
  }
  const h16* A  = qkv + ((size_t)(is_sig ? 0 : 3) * BH + bh) * NN * DH;
  const h16* Bv = qkv + ((size_t)(is_sig ? 1 : 2) * BH + bh) * NN * DH;
  h16* out = (is_sig ? sig : term) + (size_t)lz * NN * NN;
  int lane = threadIdx.x & 63, wv = threadIdx.x >> 6;
  int wy = wv >> 1, wx = wv & 1;
  int r0 = rt * 128 + 64 * wy, c0 = jt * 128 + 64 * wx;
  int kb = 8 * (lane >> 4);
  f32x4 acc[4][4] = {};
  const h16* ap = A + (size_t)(r0 + (lane & 15)) * DH + kb;
  const h16* bp = Bv + (size_t)(c0 + (lane & 15)) * DH + kb;
#pragma unroll
  for (int ks = 0; ks < 2; ks++) {
    h16x8 af[4], bfv[4];
#pragma unroll
    for (int i = 0; i < 4; i++) af[i] = *(const h16x8*)(ap + (size_t)(16 * i) * DH + 32 * ks);
#pragma unroll
    for (int j = 0; j < 4; j++) bfv[j] = *(const h16x8*)(bp + (size_t)(16 * j) * DH + 32 * ks);
#pragma unroll
    for (int i = 0; i < 4; i++)
#pragma unroll
      for (int j = 0; j < 4; j++) acc[i][j] = mfma16(af[i], bfv[j], acc[i][j]);
  }
  __shared__ h16 Clds[128][136];
#pragma unroll
  for (int i = 0; i < 4; i++)
#pragma unroll
    for (int j = 0; j < 4; j++)
#pragma unroll
      for (int r = 0; r < 4; r++) {
        int rloc = 64 * wy + 16 * i + (lane >> 4) * 4 + r;
        int cloc = 64 * wx + 16 * j + (lane & 15);
        int gr = rt * 128 + rloc;
        int gj = jt * 128 + cloc;
        float v = acc[i][j][r];
        float o;
        if (!is_sig) o = (gj <= gr) ? v : 0.f;
        else         o = (gj > gr) ? 1.f / (1.f + __expf(-v)) : 0.f;
        Clds[rloc][cloc] = (h16)o;
      }
  __syncthreads();
  int t = threadIdx.x;
  int rloc = t >> 1, half = t & 1;
  h16* dst = out + (size_t)(rt * 128 + rloc) * NN + jt * 128 + 64 * half;
#pragma unroll
  for (int e = 0; e < 8; e++)
    *(h16x8*)(dst + 8 * e) = *(const h16x8*)&Clds[rloc][64 * half + 8 * e];
}

// ---------------- scores = Qc_s.Kc^T - silu(term @ sig^T), causal mask ----------------
// 256x256 tile, 8 waves (2Mx4N), BK=64, double-buffered LDS, counted vmcnt prefetch,
// row-XOR swizzled LDS (write via pre-swizzled global src, read via XOR'd ds_read addr).
__global__ __launch_bounds__(512, 2) void k_scores(const h16* __restrict__ qkv,
                                                   const h16* __restrict__ term, const h16* __restrict__ sig,
                                                   h16* __restrict__ scores, int bh0) {
  __shared__ h16 lds[65536];  // 128 KB: 2 bufs x (A 256x64 + B 256x64); reused as C 256x256 in epilogue
  int lz = blockIdx.z, bh = bh0 + lz;
  // diagonal-descending decode: longest j-loops dispatched first
  int rem = blockIdx.x, d = 7, cnt = 1;
  while (rem >= cnt) { rem -= cnt; --d; cnt = 8 - d; }
  int Kt = rem, It = Kt + d;
  const h16* Ab = term + (size_t)lz * NN * NN + (size_t)(It * 256) * NN;
  const h16* Bb = sig + (size_t)lz * NN * NN + (size_t)(Kt * 256) * NN;
  int j0 = Kt * 256;
  int nt = (It - Kt + 1) * 4;  // BK=64 steps
  int lane = threadIdx.x & 63, wv = threadIdx.x >> 6;
  int wy = wv >> 2, wx = wv & 3;  // 2 (M) x 4 (N) waves; wave tile 128x64
  int l15 = lane & 15, q4 = lane >> 4;
  int srow = lane >> 3, schunk = lane & 7;

  f32x4 acc[8][4] = {};

#define STAGE(tt)                                                                   \
  {                                                                                 \
    int js_ = j0 + (tt) * 64;                                                       \
    h16* A_l = lds + 32768 * ((tt) & 1);                                            \
    h16* B_l = A_l + 16384;                                                         \
    _Pragma("unroll")                                                               \
    for (int inst = 0; inst < 4; inst++) {                                          \
      int rbase = 32 * wv + 8 * inst;                                               \
      int r = rbase + srow;                                                         \
      int sc_ = (schunk ^ (r & 7)) * 8;                                             \
      glds16(Ab + (size_t)r * NN + js_ + sc_, A_l + rbase * 64);                    \
      glds16(Bb + (size_t)r * NN + js_ + sc_, B_l + rbase * 64);                    \
    }                                                                               \
  }

  STAGE(0);
  for (int t = 0; t < nt; ++t) {
    const h16* A_l = lds + 32768 * (t & 1);
    const h16* B_l = A_l + 16384;
    if (t + 1 < nt) {
      STAGE(t + 1);
      asm volatile("s_waitcnt vmcnt(8)" ::: "memory");
    } else {
      asm volatile("s_waitcnt vmcnt(0)" ::: "memory");
    }
    __builtin_amdgcn_s_barrier();
    __builtin_amdgcn_sched_barrier(0);
#pragma unroll
    for (int ks = 0; ks < 2; ks++) {
      int colh = 32 * ks + 8 * q4;
      h16x8 bf[4];
#pragma unroll
      for (int n = 0; n < 4; n++) {
        int row = 64 * wx + 16 * n + l15;
        int off = (row * 128 + colh * 2) ^ ((row & 7) << 4);
        bf[n] = *(const h16x8*)((const char*)B_l + off);
      }
#pragma unroll
      for (int mh = 0; mh < 2; mh++) {
        h16x8 af[4];
#pragma unroll
        for (int m = 0; m < 4; m++) {
          int row = 128 * wy + 64 * mh + 16 * m + l15;
          int off = (row * 128 + colh * 2) ^ ((row & 7) << 4);
          af[m] = *(const h16x8*)((const char*)A_l + off);
        }
        __builtin_amdgcn_s_setprio(1);
#pragma unroll
        for (int m = 0; m < 4; m++)
#pragma unroll
          for (int n = 0; n < 4; n++)
            acc[4 * mh + m][n] = mfma16(af[m], bf[n], acc[4 * mh + m][n]);
        __builtin_amdgcn_s_setprio(0);
      }
    }
    __builtin_amdgcn_s_barrier();
  }
#undef STAGE

  // acc = -silu(S_u)
#pragma unroll
  for (int m = 0; m < 8; m++)
#pragma unroll
    for (int n = 0; n < 4; n++)
#pragma unroll
      for (int r = 0; r < 4; r++) {
        float xv = acc[m][n][r];
        acc[m][n][r] = -xv / (1.f + __expf(-xv));
      }
  // acc += Qc_s . Kc^T
  const h16* Q  = qkv + ((size_t)3 * BH + bh) * NN * DH;
  const h16* Kc = qkv + ((size_t)4 * BH + bh) * NN * DH;
#pragma unroll
  for (int d2 = 0; d2 < 2; d2++) {
    int kb = 32 * d2 + 8 * q4;
    h16x8 bq[4];
#pragma unroll
    for (int n = 0; n < 4; n++)
      bq[n] = *(const h16x8*)(Kc + (size_t)(Kt * 256 + 64 * wx + 16 * n + l15) * DH + kb);
#pragma unroll
    for (int m = 0; m < 8; m++) {
      h16x8 af = *(const h16x8*)(Q + (size_t)(It * 256 + 128 * wy + 16 * m + l15) * DH + kb);
#pragma unroll
      for (int n = 0; n < 4; n++) acc[m][n] = mfma16(af, bq[n], acc[m][n]);
    }
  }
  // epilogue: mask, stage 256x256 in LDS, coalesced writes
  __syncthreads();
#pragma unroll
  for (int m = 0; m < 8; m++)
#pragma unroll
    for (int n = 0; n < 4; n++)
#pragma unroll
      for (int r = 0; r < 4; r++) {
        int rloc = 128 * wy + 16 * m + 4 * q4 + r;
        int cloc = 64 * wx + 16 * n + l15;
        float v = (Kt * 256 + cloc <= It * 256 + rloc) ? acc[m][n][r] : -__builtin_inff();
        lds[rloc * 256 + cloc] = (h16)v;
      }
  __syncthreads();
  h16* sc = scores + (size_t)lz * NN * NN;
  int t = threadIdx.x;
  int row = t >> 1, half = t & 1;
  h16* dst = sc + (size_t)(It * 256 + row) * NN + Kt * 256 + 128 * half;
  const h16* src = lds + row * 256 + 128 * half;
#pragma unroll
  for (int e = 0; e < 16; e++)
    *(h16x8*)(dst + 8 * e) = *(const h16x8*)(src + 8 * e);
}

// ---------------- fused softmax + PV: attn_out = softmax(scores) @ Vc ----------------
__global__ __launch_bounds__(256) void k_pv(const h16* __restrict__ P, const h16* __restrict__ vcT,
                                            h16* __restrict__ attn, int bh0) {
  int It64 = blockIdx.x, lz = blockIdx.z, bh = bh0 + lz;
  int lane = threadIdx.x & 63, wv = threadIdx.x >> 6;
  int l15 = lane & 15, q4 = lane >> 4, kb = 8 * q4;
  const h16* Pb = P + (size_t)lz * NN * NN;
  const h16* VT = vcT + (size_t)bh * DH * NN;  // [d][n]
  int i0 = It64 * 64;
  int kend = ((i0 >> 8) + 1) << 8;  // 256-aligned written extent
  const h16* prow = Pb + (size_t)(i0 + 16 * wv + l15) * NN;
  // pass 1a: row max
  float m = -__builtin_inff();
  for (int kk = 0; kk < kend; kk += 32) {
    h16x8 v = *(const h16x8*)(prow + kk + kb);
#pragma unroll
    for (int e = 0; e < 8; e++) m = fmaxf(m, (float)v[e]);
  }
  m = fmaxf(m, __shfl_xor(m, 16));
  m = fmaxf(m, __shfl_xor(m, 32));
  // pass 1b: row sum of exp
  float s = 0.f;
  for (int kk = 0; kk < kend; kk += 32) {
    h16x8 v = *(const h16x8*)(prow + kk + kb);
#pragma unroll
    for (int e = 0; e < 8; e++) s += __expf((float)v[e] - m);
  }
  s += __shfl_xor(s, 16);
  s += __shfl_xor(s, 32);
  float inv = 1.f / s;
  // pass 2: PV with on-the-fly normalized A fragments
  f32x4 acc[4] = {};
  for (int kk = 0; kk < kend; kk += 32) {
    h16x8 raw = *(const h16x8*)(prow + kk + kb);
    h16x8 af;
#pragma unroll
    for (int e = 0; e < 8; e++) af[e] = (h16)(__expf((float)raw[e] - m) * inv);
#pragma unroll
    for (int c = 0; c < 4; c++) {
      h16x8 bfv = *(const h16x8*)(VT + (size_t)(16 * c + l15) * NN + kk + kb);
      acc[c] = mfma16(af, bfv, acc[c]);
    }
  }
  // stage 64x64 tile in LDS, coalesced write
  __shared__ h16 tl[64][72];
  int ri = 16 * wv + 4 * q4;
#pragma unroll
  for (int c = 0; c < 4; c++)
#pragma unroll
    for (int r = 0; r < 4; r++) tl[ri + r][l15 + 16 * c] = (h16)acc[c][r];
  __syncthreads();
  int t = threadIdx.x;
  int row = t >> 2, cg = (t & 3) * 16;
  int hh = bh & 7, b = bh >> 3;
  h16* dst = attn + ((size_t)b * NN + i0 + row) * DIM + hh * DH + cg;
  *(h16x8*)dst = *(const h16x8*)&tl[row][cg];
  *(h16x8*)(dst + 8) = *(const h16x8*)&tl[row][cg + 8];
}

// ---------------- output projection (fp32 out) ----------------
__global__ __launch_bounds__(256) void k_outproj(const h16* __restrict__ attn, const h16* __restrict__ Wt,
                                                 float* __restrict__ out) {
  int m0 = blockIdx.x * 64, o0 = blockIdx.y * 64;
  int lane = threadIdx.x & 63, wv = threadIdx.x >> 6;
  int kb = 8 * (lane >> 4);
  f32x4 acc[4] = {};
  const h16* ap = attn + (size_t)(m0 + 16 * wv + (lane & 15)) * DIM + kb;
  const h16* bp = Wt + (size_t)(o0 + (lane & 15)) * DIM + kb;
  for (int k0 = 0; k0 < DIM; k0 += 32) {
    h16x8 af = *(const h16x8*)(ap + k0);
#pragma unroll
    for (int t = 0; t < 4; t++) {
      h16x8 bfv = *(const h16x8*)(bp + (size_t)(16 * t) * DIM + k0);
      acc[t] = mfma16(af, bfv, acc[t]);
    }
  }
  int ri = m0 + 16 * wv + (lane >> 4) * 4;
  int c0 = o0 + (lane & 15);
#pragma unroll
  for (int t = 0; t < 4; t++)
#pragma unroll
    for (int r = 0; r < 4; r++) out[(size_t)(ri + r) * DIM + c0 + 16 * t] = acc[t][r];
}

// ---------------- launch ----------------

extern "C" void kernel_launch(void* const* d_in, const int* in_sizes, int n_in,
                              void* d_out, int out_size, void* d_ws, size_t ws_size,
                              hipStream_t stream) {
  const float* x = (const float*)d_in[0];
  WPtrs wp;
  for (int i = 0; i < 7; i++) wp.w[i] = (const float*)d_in[1 + i];

  char* p = (char*)d_ws;
  auto alloc = [&](size_t bytes) {
    void* r = (void*)p;
    p += (bytes + 255) & ~(size_t)255;
    return r;
  };
  h16* xh   = (h16*)alloc((size_t)4096 * DIM * 2);            // 4 MB
  h16* wt   = (h16*)alloc((size_t)7 * DIM * DIM * 2);         // 3.5 MB
  h16* qkv  = (h16*)alloc((size_t)6 * BH * NN * DH * 2);      // 24 MB
  h16* vcT  = (h16*)alloc((size_t)BH * DH * NN * 2);          // 4 MB
  h16* attn = (h16*)alloc((size_t)4096 * DIM * 2);            // 4 MB
  size_t used = (size_t)(p - (char*)d_ws);
  size_t per_bh = (size_t)NN * NN * 2;                        // 8 MB
  size_t avail = ws_size > used ? ws_size - used : 0;
  int CH = 16;
  while (CH > 1 && (size_t)CH * per_bh * 3 > avail) CH >>= 1;
  h16* term   = (h16*)alloc((size_t)CH * per_bh);
  h16* sig    = (h16*)alloc((size_t)CH * per_bh);
  h16* scores = (h16*)alloc((size_t)CH * per_bh);

  k_pack_x<<<dim3(2048), dim3(256), 0, stream>>>(x, xh);
  k_pack_w<<<dim3(8, 8, 7), dim3(256), 0, stream>>>(wp, wt);
  k_proj<<<dim3(32, 24), dim3(256), 0, stream>>>(xh, wt, qkv, vcT);

  for (int c0 = 0; c0 < BH; c0 += CH) {
    k_termsig<<<dim3(152, 2, CH), dim3(256), 0, stream>>>(qkv, term, sig, c0);
    k_scores<<<dim3(36, 1, CH), dim3(512), 0, stream>>>(qkv, term, sig, scores, c0);
    k_pv<<<dim3(NN / 64, 1, CH), dim3(256), 0, stream>>>(scores, vcT, attn, c0);
  }

  k_outproj<<<dim3(64, 8), dim3(256), 0, stream>>>(attn, wt + (size_t)6 * DIM * DIM, (float*)d_out);
}

// Round 6
// 412.682 us; speedup vs baseline: 1.1554x; 1.1554x over previous
//
#include <hip/hip_runtime.h>
#include <hip/hip_bf16.h>

typedef _Float16 h16;
typedef _Float16 h16x8 __attribute__((ext_vector_type(8)));
typedef float f32x4 __attribute__((ext_vector_type(4)));

#define DEVI static __device__ __forceinline__

constexpr int NN = 2048;     // sequence length
constexpr int DIM = 512;
constexpr int NH = 8;
constexpr int DH = 64;
constexpr int BH = 16;       // B * H
constexpr float FSCALE = 0.125f;  // DH^-0.5

DEVI f32x4 mfma16(h16x8 a, h16x8 b, f32x4 c) {
  return __builtin_amdgcn_mfma_f32_16x16x32_f16(a, b, c, 0, 0, 0);
}

DEVI void glds16(const void* g, void* l) {
  __builtin_amdgcn_global_load_lds(
      (const __attribute__((address_space(1))) unsigned int*)g,
      (__attribute__((address_space(3))) unsigned int*)l, 16, 0, 0);
}

DEVI void tri_decode(int p, int& a, int& b) {
  a = (int)((sqrtf(8.f * p + 1.f) - 1.f) * 0.5f);
  while ((a + 1) * (a + 2) / 2 <= p) ++a;
  while (a * (a + 1) / 2 > p) --a;
  b = p - a * (a + 1) / 2;
}

// ---------------- pack kernels ----------------

__global__ __launch_bounds__(256) void k_pack_x(const float* __restrict__ x, h16* __restrict__ xh) {
  int i = (blockIdx.x * 256 + threadIdx.x) * 4;
  float4 v = *(const float4*)(x + i);
  union { h16 h[4]; uint2 u; } pk;
  pk.h[0] = (h16)v.x; pk.h[1] = (h16)v.y; pk.h[2] = (h16)v.z; pk.h[3] = (h16)v.w;
  *(uint2*)(xh + i) = pk.u;
}

struct WPtrs { const float* w[7]; };

// transpose+cast each 512x512 weight: wt[o][k] = W[k][o]
__global__ __launch_bounds__(256) void k_pack_w(WPtrs wp, h16* __restrict__ wt) {
  const float* W = wp.w[blockIdx.z];
  h16* out = wt + (size_t)blockIdx.z * DIM * DIM;
  __shared__ h16 t[64][65];
  int k0 = blockIdx.x * 64, o0 = blockIdx.y * 64;
  int c = threadIdx.x & 63, r4 = threadIdx.x >> 6;
#pragma unroll
  for (int rr = 0; rr < 64; rr += 4) {
    int r = rr + r4;
    t[r][c] = (h16)W[(size_t)(k0 + r) * DIM + o0 + c];
  }
  __syncthreads();
#pragma unroll
  for (int rr = 0; rr < 64; rr += 4) {
    int r = rr + r4;
    out[(size_t)(o0 + r) * DIM + k0 + c] = t[c][r];
  }
}

// ---------------- fused QKV projection ----------------
__global__ __launch_bounds__(256) void k_proj(const h16* __restrict__ xh, const h16* __restrict__ wt,
                                              h16* __restrict__ qkv, h16* __restrict__ vcT) {
  __shared__ h16 pool[128 * 136];
  h16* Al = pool;
  h16* Bl = pool + 128 * 64;
  int m0 = blockIdx.x * 128, o0 = blockIdx.y * 128;
  int lane = threadIdx.x & 63, wv = threadIdx.x >> 6;
  int wy = wv >> 1, wx = wv & 1;
  int srow = 32 * wv;
  int lr = lane >> 3, lc = 8 * (lane & 7);
  f32x4 acc[4][4] = {};
  for (int ks0 = 0; ks0 < DIM; ks0 += 64) {
#pragma unroll
    for (int inst = 0; inst < 4; inst++) {
      int r = srow + 8 * inst;
      glds16(xh + (size_t)(m0 + r + lr) * DIM + ks0 + lc, Al + r * 64);
      glds16(wt + (size_t)(o0 + r + lr) * DIM + ks0 + lc, Bl + r * 64);
    }
    __syncthreads();
#pragma unroll
    for (int ks = 0; ks < 2; ks++) {
      h16x8 af[4], bfv[4];
      int co = 32 * ks + 8 * (lane >> 4);
#pragma unroll
      for (int i = 0; i < 4; i++) af[i] = *(const h16x8*)(Al + (64 * wy + 16 * i + (lane & 15)) * 64 + co);
#pragma unroll
      for (int j = 0; j < 4; j++) bfv[j] = *(const h16x8*)(Bl + (64 * wx + 16 * j + (lane & 15)) * 64 + co);
#pragma unroll
      for (int i = 0; i < 4; i++)
#pragma unroll
        for (int j = 0; j < 4; j++) acc[i][j] = mfma16(af[i], bfv[j], acc[i][j]);
    }
    __syncthreads();
  }
  int widx = o0 >> 9;
  float scl = (widx == 0 || widx == 3) ? FSCALE : 1.0f;
  h16 (*Clds)[136] = (h16(*)[136])pool;
#pragma unroll
  for (int i = 0; i < 4; i++)
#pragma unroll
    for (int j = 0; j < 4; j++)
#pragma unroll
      for (int r = 0; r < 4; r++) {
        int rloc = 64 * wy + 16 * i + (lane >> 4) * 4 + r;
        int cloc = 64 * wx + 16 * j + (lane & 15);
        Clds[rloc][cloc] = (h16)(acc[i][j][r] * scl);
      }
  __syncthreads();
  int t = threadIdx.x;
  {
    int rloc = t >> 1, half = t & 1;
    int gi = m0 + rloc;
    int b = gi >> 11, n = gi & 2047;
    int og = o0 + 64 * half;
    int h = (og >> 6) & 7;
    h16* dst = qkv + (((size_t)widx * BH + b * NH + h) * NN + n) * DH;
#pragma unroll
    for (int e = 0; e < 8; e++)
      *(h16x8*)(dst + 8 * e) = *(const h16x8*)&Clds[rloc][64 * half + 8 * e];
  }
  if (widx == 5) {
    int c = t & 127, rq = t >> 7;
    int og = o0 + c;
    int h = (og >> 6) & 7, d = og & 63;
    int b = m0 >> 11, nb = (m0 & 2047) + rq * 64;
    h16* dst = vcT + ((size_t)(b * NH + h) * DH + d) * NN + nb;
#pragma unroll
    for (int g = 0; g < 8; g++) {
      h16x8 w;
#pragma unroll
      for (int e = 0; e < 8; e++) w[e] = Clds[rq * 64 + 8 * g + e][c];
      *(h16x8*)(dst + 8 * g) = w;
    }
  }
}

// ---------------- term1 & sigmoid matrices ----------------
// term[i][j] = (Qc_s[i].Vu[j]) * [j<=i]; sig[k][j] = sigmoid(Qu_s[k].Ku[j]) * [j>k]
// pidx < 136: triangular pairs. 136..143: (2m, 2m+1) both. 144..151: (2m+1, 2m) sig only.
__global__ __launch_bounds__(256) void k_termsig(const h16* __restrict__ qkv,
                                                 h16* __restrict__ term, h16* __restrict__ sig, int bh0) {
  int pidx = blockIdx.x;
  bool is_sig = blockIdx.y != 0;
  int lz = blockIdx.z, bh = bh0 + lz;
  int rt, jt;
  if (pidx >= 144) {
    if (!is_sig) return;
    int mm = pidx - 144;
    rt = 2 * mm + 1; jt = 2 * mm;
  } else if (pidx >= 136) {
    int mm = pidx - 136;
    rt = 2 * mm; jt = 2 * mm + 1;
  } else {
    int a, bq;
    tri_decode(pidx, a, bq);
    rt = is_sig ? bq : a;
    jt = is_sig ? a : bq;
  }
  const h16* A  = qkv + ((size_t)(is_sig ? 0 : 3) * BH + bh) * NN * DH;
  const h16* Bv = qkv + ((size_t)(is_sig ? 1 : 2) * BH + bh) * NN * DH;
  h16* out = (is_sig ? sig : term) + (size_t)lz * NN * NN;
  int lane = threadIdx.x & 63, wv = threadIdx.x >> 6;
  int wy = wv >> 1, wx = wv & 1;
  int r0 = rt * 128 + 64 * wy, c0 = jt * 128 + 64 * wx;
  int kb = 8 * (lane >> 4);
  f32x4 acc[4][4] = {};
  const h16* ap = A + (size_t)(r0 + (lane & 15)) * DH + kb;
  const h16* bp = Bv + (size_t)(c0 + (lane & 15)) * DH + kb;
#pragma unroll
  for (int ks = 0; ks < 2; ks++) {
    h16x8 af[4], bfv[4];
#pragma unroll
    for (int i = 0; i < 4; i++) af[i] = *(const h16x8*)(ap + (size_t)(16 * i) * DH + 32 * ks);
#pragma unroll
    for (int j = 0; j < 4; j++) bfv[j] = *(const h16x8*)(bp + (size_t)(16 * j) * DH + 32 * ks);
#pragma unroll
    for (int i = 0; i < 4; i++)
#pragma unroll
      for (int j = 0; j < 4; j++) acc[i][j] = mfma16(af[i], bfv[j], acc[i][j]);
  }
  __shared__ h16 Clds[128][136];
#pragma unroll
  for (int i = 0; i < 4; i++)
#pragma unroll
    for (int j = 0; j < 4; j++)
#pragma unroll
      for (int r = 0; r < 4; r++) {
        int rloc = 64 * wy + 16 * i + (lane >> 4) * 4 + r;
        int cloc = 64 * wx + 16 * j + (lane & 15);
        int gr = rt * 128 + rloc;
        int gj = jt * 128 + cloc;
        float v = acc[i][j][r];
        float o;
        if (!is_sig) o = (gj <= gr) ? v : 0.f;
        else         o = (gj > gr) ? 1.f / (1.f + __expf(-v)) : 0.f;
        Clds[rloc][cloc] = (h16)o;
      }
  __syncthreads();
  int t = threadIdx.x;
  int rloc = t >> 1, half = t & 1;
  h16* dst = out + (size_t)(rt * 128 + rloc) * NN + jt * 128 + 64 * half;
#pragma unroll
  for (int e = 0; e < 8; e++)
    *(h16x8*)(dst + 8 * e) = *(const h16x8*)&Clds[rloc][64 * half + 8 * e];
}

// ---------------- scores = Qc_s.Kc^T - silu(term @ sig^T), causal mask ----------------
// 256x256 tile, 8 waves, BK=64, dbuf LDS, counted vmcnt, XOR swizzle.
// Flat grid (36*CH blocks): bijective XCD swizzle (CH-agnostic, m204 form);
// within each slice tiles run It-descending for A-panel L2 reuse.
__global__ __launch_bounds__(512, 2) void k_scores(const h16* __restrict__ qkv,
                                                   const h16* __restrict__ term, const h16* __restrict__ sig,
                                                   h16* __restrict__ scores, int bh0) {
  __shared__ h16 lds[65536];  // 128 KB
  int nwg = gridDim.x;
  int q = nwg >> 3, rmd = nwg & 7;
  int xcd = blockIdx.x & 7, idx = blockIdx.x >> 3;
  int wg = (xcd < rmd) ? xcd * (q + 1) + idx : rmd * (q + 1) + (xcd - rmd) * q + idx;
  int lz = wg / 36, r = wg % 36;
  int It = 7, base = 0;
  while (r - base >= It + 1) { base += It + 1; --It; }
  int Kt = r - base;
  int bh = bh0 + lz;
  const h16* Ab = term + (size_t)lz * NN * NN + (size_t)(It * 256) * NN;
  const h16* Bb = sig + (size_t)lz * NN * NN + (size_t)(Kt * 256) * NN;
  int j0 = Kt * 256;
  int nt = (It - Kt + 1) * 4;  // BK=64 steps
  int lane = threadIdx.x & 63, wv = threadIdx.x >> 6;
  int wy = wv >> 2, wx = wv & 3;  // 2 (M) x 4 (N) waves; wave tile 128x64
  int l15 = lane & 15, q4 = lane >> 4;
  int srow = lane >> 3, schunk = lane & 7;

  f32x4 acc[8][4] = {};

#define STAGE(tt)                                                                   \
  {                                                                                 \
    int js_ = j0 + (tt) * 64;                                                       \
    h16* A_l = lds + 32768 * ((tt) & 1);                                            \
    h16* B_l = A_l + 16384;                                                         \
    _Pragma("unroll")                                                               \
    for (int inst = 0; inst < 4; inst++) {                                          \
      int rbase = 32 * wv + 8 * inst;                                               \
      int rr = rbase + srow;                                                        \
      int sc_ = (schunk ^ (rr & 7)) * 8;                                            \
      glds16(Ab + (size_t)rr * NN + js_ + sc_, A_l + rbase * 64);                   \
      glds16(Bb + (size_t)rr * NN + js_ + sc_, B_l + rbase * 64);                   \
    }                                                                               \
  }

  STAGE(0);
  for (int t = 0; t < nt; ++t) {
    const h16* A_l = lds + 32768 * (t & 1);
    const h16* B_l = A_l + 16384;
    if (t + 1 < nt) {
      STAGE(t + 1);
      asm volatile("s_waitcnt vmcnt(8)" ::: "memory");
    } else {
      asm volatile("s_waitcnt vmcnt(0)" ::: "memory");
    }
    __builtin_amdgcn_s_barrier();
    __builtin_amdgcn_sched_barrier(0);
#pragma unroll
    for (int ks = 0; ks < 2; ks++) {
      int colh = 32 * ks + 8 * q4;
      h16x8 bf[4];
#pragma unroll
      for (int n = 0; n < 4; n++) {
        int row = 64 * wx + 16 * n + l15;
        int off = (row * 128 + colh * 2) ^ ((row & 7) << 4);
        bf[n] = *(const h16x8*)((const char*)B_l + off);
      }
#pragma unroll
      for (int mh = 0; mh < 2; mh++) {
        h16x8 af[4];
#pragma unroll
        for (int m = 0; m < 4; m++) {
          int row = 128 * wy + 64 * mh + 16 * m + l15;
          int off = (row * 128 + colh * 2) ^ ((row & 7) << 4);
          af[m] = *(const h16x8*)((const char*)A_l + off);
        }
        __builtin_amdgcn_s_setprio(1);
#pragma unroll
        for (int m = 0; m < 4; m++)
#pragma unroll
          for (int n = 0; n < 4; n++)
            acc[4 * mh + m][n] = mfma16(af[m], bf[n], acc[4 * mh + m][n]);
        __builtin_amdgcn_s_setprio(0);
      }
    }
    __builtin_amdgcn_s_barrier();
  }
#undef STAGE

  // acc = -silu(S_u)
#pragma unroll
  for (int m = 0; m < 8; m++)
#pragma unroll
    for (int n = 0; n < 4; n++)
#pragma unroll
      for (int rr = 0; rr < 4; rr++) {
        float xv = acc[m][n][rr];
        acc[m][n][rr] = -xv / (1.f + __expf(-xv));
      }
  // acc += Qc_s . Kc^T
  const h16* Q  = qkv + ((size_t)3 * BH + bh) * NN * DH;
  const h16* Kc = qkv + ((size_t)4 * BH + bh) * NN * DH;
#pragma unroll
  for (int d2 = 0; d2 < 2; d2++) {
    int kb = 32 * d2 + 8 * q4;
    h16x8 bq[4];
#pragma unroll
    for (int n = 0; n < 4; n++)
      bq[n] = *(const h16x8*)(Kc + (size_t)(Kt * 256 + 64 * wx + 16 * n + l15) * DH + kb);
#pragma unroll
    for (int m = 0; m < 8; m++) {
      h16x8 af = *(const h16x8*)(Q + (size_t)(It * 256 + 128 * wy + 16 * m + l15) * DH + kb);
#pragma unroll
      for (int n = 0; n < 4; n++) acc[m][n] = mfma16(af, bq[n], acc[m][n]);
    }
  }
  // epilogue: mask, stage 256x256 in LDS, coalesced writes
  __syncthreads();
#pragma unroll
  for (int m = 0; m < 8; m++)
#pragma unroll
    for (int n = 0; n < 4; n++)
#pragma unroll
      for (int rr = 0; rr < 4; rr++) {
        int rloc = 128 * wy + 16 * m + 4 * q4 + rr;
        int cloc = 64 * wx + 16 * n + l15;
        float v = (Kt * 256 + cloc <= It * 256 + rloc) ? acc[m][n][rr] : -__builtin_inff();
        lds[rloc * 256 + cloc] = (h16)v;
      }
  __syncthreads();
  h16* sc = scores + (size_t)lz * NN * NN;
  int t = threadIdx.x;
  int row = t >> 1, half = t & 1;
  h16* dst = sc + (size_t)(It * 256 + row) * NN + Kt * 256 + 128 * half;
  const h16* src = lds + row * 256 + 128 * half;
#pragma unroll
  for (int e = 0; e < 16; e++)
    *(h16x8*)(dst + 8 * e) = *(const h16x8*)(src + 8 * e);
}

// ---------------- row softmax (in place, fp16 scores -> fp16 probs) ----------------
__global__ __launch_bounds__(256) void k_softmax(h16* __restrict__ sbuf) {
  int lane = threadIdx.x & 63, wv = threadIdx.x >> 6;
  int i = blockIdx.x * 4 + wv;
  int lz = blockIdx.y;
  h16* srow = sbuf + ((size_t)lz * NN + i) * NN;
  int kend = ((i >> 7) + 1) << 7;  // 128-aligned end of processed region
  float v[32];
  float m = -__builtin_inff();
#pragma unroll
  for (int it = 0; it < 4; it++) {
    int base = it * 512 + lane * 8;
    if (base < kend) {
      h16x8 raw = *(const h16x8*)(srow + base);
#pragma unroll
      for (int e = 0; e < 8; e++) {
        float xv = (float)raw[e];
        v[it * 8 + e] = xv;
        m = fmaxf(m, xv);
      }
    } else {
#pragma unroll
      for (int e = 0; e < 8; e++) v[it * 8 + e] = -__builtin_inff();
    }
  }
#pragma unroll
  for (int off = 32; off > 0; off >>= 1) m = fmaxf(m, __shfl_xor(m, off));
  float s = 0.f;
#pragma unroll
  for (int t = 0; t < 32; t++) {
    float e = __expf(v[t] - m);
    v[t] = e;
    s += e;
  }
#pragma unroll
  for (int off = 32; off > 0; off >>= 1) s += __shfl_xor(s, off);
  float inv = 1.f / s;
#pragma unroll
  for (int it = 0; it < 4; it++) {
    int base = it * 512 + lane * 8;
    if (base < kend) {
      h16x8 o;
#pragma unroll
      for (int e = 0; e < 8; e++) o[e] = (h16)(v[it * 8 + e] * inv);
      *(h16x8*)(srow + base) = o;
    }
  }
}

// ---------------- PV: attn_out = P @ Vc (64-row tiles) ----------------
__global__ __launch_bounds__(256) void k_pv(const h16* __restrict__ P, const h16* __restrict__ vcT,
                                            h16* __restrict__ attn, int bh0) {
  int It64 = blockIdx.x, lz = blockIdx.z, bh = bh0 + lz;
  int lane = threadIdx.x & 63, wv = threadIdx.x >> 6;
  const h16* Pb = P + (size_t)lz * NN * NN;
  const h16* VT = vcT + (size_t)bh * DH * NN;  // [d][n]
  int i0 = It64 * 64;
  int kend = ((It64 >> 1) + 1) << 7;  // 128-aligned end of causal row extent
  f32x4 acc[4] = {};
  int kb = 8 * (lane >> 4);
  const h16* prow = Pb + (size_t)(i0 + 16 * wv + (lane & 15)) * NN;
  for (int kk = 0; kk < kend; kk += 32) {
    h16x8 af = *(const h16x8*)(prow + kk + kb);
#pragma unroll
    for (int c = 0; c < 4; c++) {
      h16x8 bfv = *(const h16x8*)(VT + (size_t)(16 * c + (lane & 15)) * NN + kk + kb);
      acc[c] = mfma16(af, bfv, acc[c]);
    }
  }
  int hh = bh & 7, b = bh >> 3;
  int ri = i0 + 16 * wv + (lane >> 4) * 4;
  int cd0 = lane & 15;
#pragma unroll
  for (int c = 0; c < 4; c++)
#pragma unroll
    for (int r = 0; r < 4; r++) {
      int gi = ri + r, gd = cd0 + 16 * c;
      attn[((size_t)b * NN + gi) * DIM + hh * DH + gd] = (h16)acc[c][r];
    }
}

// ---------------- output projection (fp32 out) ----------------
__global__ __launch_bounds__(256) void k_outproj(const h16* __restrict__ attn, const h16* __restrict__ Wt,
                                                 float* __restrict__ out) {
  int m0 = blockIdx.x * 64, o0 = blockIdx.y * 64;
  int lane = threadIdx.x & 63, wv = threadIdx.x >> 6;
  int kb = 8 * (lane >> 4);
  f32x4 acc[4] = {};
  const h16* ap = attn + (size_t)(m0 + 16 * wv + (lane & 15)) * DIM + kb;
  const h16* bp = Wt + (size_t)(o0 + (lane & 15)) * DIM + kb;
  for (int k0 = 0; k0 < DIM; k0 += 32) {
    h16x8 af = *(const h16x8*)(ap + k0);
#pragma unroll
    for (int t = 0; t < 4; t++) {
      h16x8 bfv = *(const h16x8*)(bp + (size_t)(16 * t) * DIM + k0);
      acc[t] = mfma16(af, bfv, acc[t]);
    }
  }
  int ri = m0 + 16 * wv + (lane >> 4) * 4;
  int c0 = o0 + (lane & 15);
#pragma unroll
  for (int t = 0; t < 4; t++)
#pragma unroll
    for (int r = 0; r < 4; r++) out[(size_t)(ri + r) * DIM + c0 + 16 * t] = acc[t][r];
}

// ---------------- launch ----------------

extern "C" void kernel_launch(void* const* d_in, const int* in_sizes, int n_in,
                              void* d_out, int out_size, void* d_ws, size_t ws_size,
                              hipStream_t stream) {
  const float* x = (const float*)d_in[0];
  WPtrs wp;
  for (int i = 0; i < 7; i++) wp.w[i] = (const float*)d_in[1 + i];

  char* p = (char*)d_ws;
  auto alloc = [&](size_t bytes) {
    void* r = (void*)p;
    p += (bytes + 255) & ~(size_t)255;
    return r;
  };
  h16* xh   = (h16*)alloc((size_t)4096 * DIM * 2);            // 4 MB
  h16* wt   = (h16*)alloc((size_t)7 * DIM * DIM * 2);         // 3.5 MB
  h16* qkv  = (h16*)alloc((size_t)6 * BH * NN * DH * 2);      // 24 MB
  h16* vcT  = (h16*)alloc((size_t)BH * DH * NN * 2);          // 4 MB
  h16* attn = (h16*)alloc((size_t)4096 * DIM * 2);            // 4 MB
  size_t used = (size_t)(p - (char*)d_ws);
  size_t per_bh = (size_t)NN * NN * 2;                        // 8 MB
  size_t avail = ws_size > used ? ws_size - used : 0;
  int CH = 16;
  while (CH > 1 && (size_t)CH * per_bh * 3 > avail) CH >>= 1;
  h16* term   = (h16*)alloc((size_t)CH * per_bh);
  h16* sig    = (h16*)alloc((size_t)CH * per_bh);
  h16* scores = (h16*)alloc((size_t)CH * per_bh);

  k_pack_x<<<dim3(2048), dim3(256), 0, stream>>>(x, xh);
  k_pack_w<<<dim3(8, 8, 7), dim3(256), 0, stream>>>(wp, wt);
  k_proj<<<dim3(32, 24), dim3(256), 0, stream>>>(xh, wt, qkv, vcT);

  for (int c0 = 0; c0 < BH; c0 += CH) {
    k_termsig<<<dim3(152, 2, CH), dim3(256), 0, stream>>>(qkv, term, sig, c0);
    k_scores<<<dim3(36 * CH), dim3(512), 0, stream>>>(qkv, term, sig, scores, c0);
    k_softmax<<<dim3(NN / 4, CH), dim3(256), 0, stream>>>(scores);
    k_pv<<<dim3(NN / 64, 1, CH), dim3(256), 0, stream>>>(scores, vcT, attn, c0);
  }

  k_outproj<<<dim3(64, 8), dim3(256), 0, stream>>>(attn, wt + (size_t)6 * DIM * DIM, (float*)d_out);
}

// Round 7
// 370.782 us; speedup vs baseline: 1.2859x; 1.1130x over previous
//
#include <hip/hip_runtime.h>
#include <hip/hip_bf16.h>

typedef _Float16 h16;
typedef _Float16 h16x8 __attribute__((ext_vector_type(8)));
typedef float f32x4 __attribute__((ext_vector_type(4)));

#define DEVI static __device__ __forceinline__

constexpr int NN = 2048;     // sequence length
constexpr int DIM = 512;
constexpr int NH = 8;
constexpr int DH = 64;
constexpr int BH = 16;       // B * H
constexpr float FSCALE = 0.125f;  // DH^-0.5

DEVI f32x4 mfma16(h16x8 a, h16x8 b, f32x4 c) {
  return __builtin_amdgcn_mfma_f32_16x16x32_f16(a, b, c, 0, 0, 0);
}

DEVI void glds16(const void* g, void* l) {
  __builtin_amdgcn_global_load_lds(
      (const __attribute__((address_space(1))) unsigned int*)g,
      (__attribute__((address_space(3))) unsigned int*)l, 16, 0, 0);
}

DEVI void tri_decode(int p, int& a, int& b) {
  a = (int)((sqrtf(8.f * p + 1.f) - 1.f) * 0.5f);
  while ((a + 1) * (a + 2) / 2 <= p) ++a;
  while (a * (a + 1) / 2 > p) --a;
  b = p - a * (a + 1) / 2;
}

// ---------------- pack kernels ----------------

__global__ __launch_bounds__(256) void k_pack_x(const float* __restrict__ x, h16* __restrict__ xh) {
  int i = (blockIdx.x * 256 + threadIdx.x) * 4;
  float4 v = *(const float4*)(x + i);
  union { h16 h[4]; uint2 u; } pk;
  pk.h[0] = (h16)v.x; pk.h[1] = (h16)v.y; pk.h[2] = (h16)v.z; pk.h[3] = (h16)v.w;
  *(uint2*)(xh + i) = pk.u;
}

struct WPtrs { const float* w[7]; };

// transpose+cast each 512x512 weight: wt[o][k] = W[k][o]
__global__ __launch_bounds__(256) void k_pack_w(WPtrs wp, h16* __restrict__ wt) {
  const float* W = wp.w[blockIdx.z];
  h16* out = wt + (size_t)blockIdx.z * DIM * DIM;
  __shared__ h16 t[64][65];
  int k0 = blockIdx.x * 64, o0 = blockIdx.y * 64;
  int c = threadIdx.x & 63, r4 = threadIdx.x >> 6;
#pragma unroll
  for (int rr = 0; rr < 64; rr += 4) {
    int r = rr + r4;
    t[r][c] = (h16)W[(size_t)(k0 + r) * DIM + o0 + c];
  }
  __syncthreads();
#pragma unroll
  for (int rr = 0; rr < 64; rr += 4) {
    int r = rr + r4;
    out[(size_t)(o0 + r) * DIM + k0 + c] = t[c][r];
  }
}

// ---------------- fused QKV projection ----------------
__global__ __launch_bounds__(256) void k_proj(const h16* __restrict__ xh, const h16* __restrict__ wt,
                                              h16* __restrict__ qkv, h16* __restrict__ vcT) {
  __shared__ h16 pool[128 * 136];
  h16* Al = pool;
  h16* Bl = pool + 128 * 64;
  int m0 = blockIdx.x * 128, o0 = blockIdx.y * 128;
  int lane = threadIdx.x & 63, wv = threadIdx.x >> 6;
  int wy = wv >> 1, wx = wv & 1;
  int srow = 32 * wv;
  int lr = lane >> 3, lc = 8 * (lane & 7);
  f32x4 acc[4][4] = {};
  for (int ks0 = 0; ks0 < DIM; ks0 += 64) {
#pragma unroll
    for (int inst = 0; inst < 4; inst++) {
      int r = srow + 8 * inst;
      glds16(xh + (size_t)(m0 + r + lr) * DIM + ks0 + lc, Al + r * 64);
      glds16(wt + (size_t)(o0 + r + lr) * DIM + ks0 + lc, Bl + r * 64);
    }
    __syncthreads();
#pragma unroll
    for (int ks = 0; ks < 2; ks++) {
      h16x8 af[4], bfv[4];
      int co = 32 * ks + 8 * (lane >> 4);
#pragma unroll
      for (int i = 0; i < 4; i++) af[i] = *(const h16x8*)(Al + (64 * wy + 16 * i + (lane & 15)) * 64 + co);
#pragma unroll
      for (int j = 0; j < 4; j++) bfv[j] = *(const h16x8*)(Bl + (64 * wx + 16 * j + (lane & 15)) * 64 + co);
#pragma unroll
      for (int i = 0; i < 4; i++)
#pragma unroll
        for (int j = 0; j < 4; j++) acc[i][j] = mfma16(af[i], bfv[j], acc[i][j]);
    }
    __syncthreads();
  }
  int widx = o0 >> 9;
  float scl = (widx == 0 || widx == 3) ? FSCALE : 1.0f;
  h16 (*Clds)[136] = (h16(*)[136])pool;
#pragma unroll
  for (int i = 0; i < 4; i++)
#pragma unroll
    for (int j = 0; j < 4; j++)
#pragma unroll
      for (int r = 0; r < 4; r++) {
        int rloc = 64 * wy + 16 * i + (lane >> 4) * 4 + r;
        int cloc = 64 * wx + 16 * j + (lane & 15);
        Clds[rloc][cloc] = (h16)(acc[i][j][r] * scl);
      }
  __syncthreads();
  int t = threadIdx.x;
  {
    int rloc = t >> 1, half = t & 1;
    int gi = m0 + rloc;
    int b = gi >> 11, n = gi & 2047;
    int og = o0 + 64 * half;
    int h = (og >> 6) & 7;
    h16* dst = qkv + (((size_t)widx * BH + b * NH + h) * NN + n) * DH;
#pragma unroll
    for (int e = 0; e < 8; e++)
      *(h16x8*)(dst + 8 * e) = *(const h16x8*)&Clds[rloc][64 * half + 8 * e];
  }
  if (widx == 5) {
    int c = t & 127, rq = t >> 7;
    int og = o0 + c;
    int h = (og >> 6) & 7, d = og & 63;
    int b = m0 >> 11, nb = (m0 & 2047) + rq * 64;
    h16* dst = vcT + ((size_t)(b * NH + h) * DH + d) * NN + nb;
#pragma unroll
    for (int g = 0; g < 8; g++) {
      h16x8 w;
#pragma unroll
      for (int e = 0; e < 8; e++) w[e] = Clds[rq * 64 + 8 * g + e][c];
      *(h16x8*)(dst + 8 * g) = w;
    }
  }
}

// ---------------- term1 & sigmoid matrices (LDS-staged operands) ----------------
// term[i][j] = (Qc_s[i].Vu[j]) * [j<=i]; sig[k][j] = sigmoid(Qu_s[k].Ku[j]) * [j>k]
// pidx < 136: triangular pairs. 136..143: (2m, 2m+1) both. 144..151: (2m+1, 2m) sig only.
__global__ __launch_bounds__(256) void k_termsig(const h16* __restrict__ qkv,
                                                 h16* __restrict__ term, h16* __restrict__ sig, int bh0) {
  int pidx = blockIdx.x;
  bool is_sig = blockIdx.y != 0;
  int lz = blockIdx.z, bh = bh0 + lz;
  int rt, jt;
  if (pidx >= 144) {
    if (!is_sig) return;
    int mm = pidx - 144;
    rt = 2 * mm + 1; jt = 2 * mm;
  } else if (pidx >= 136) {
    int mm = pidx - 136;
    rt = 2 * mm; jt = 2 * mm + 1;
  } else {
    int a, bq;
    tri_decode(pidx, a, bq);
    rt = is_sig ? bq : a;
    jt = is_sig ? a : bq;
  }
  const h16* A  = qkv + ((size_t)(is_sig ? 0 : 3) * BH + bh) * NN * DH;
  const h16* Bv = qkv + ((size_t)(is_sig ? 1 : 2) * BH + bh) * NN * DH;
  h16* out = (is_sig ? sig : term) + (size_t)lz * NN * NN;
  int lane = threadIdx.x & 63, wv = threadIdx.x >> 6;
  int wy = wv >> 1, wx = wv & 1;
  int l15 = lane & 15, q4 = lane >> 4;
  int lr = lane >> 3, lchunk = lane & 7;
  __shared__ h16 pool[128 * 136];  // stage: Al+Bl (32KB); epilogue: Clds[128][136]
  h16* Al = pool;
  h16* Bl = pool + 128 * 64;
  // one-shot stage of both 128x64 panels (swizzled source, linear dest)
#pragma unroll
  for (int inst = 0; inst < 4; inst++) {
    int rbase = 32 * wv + 8 * inst;
    int row = rbase + lr;
    int sc_ = (lchunk ^ (row & 7)) * 8;
    glds16(A + (size_t)(rt * 128 + row) * DH + sc_, Al + rbase * 64);
    glds16(Bv + (size_t)(jt * 128 + row) * DH + sc_, Bl + rbase * 64);
  }
  __syncthreads();
  f32x4 acc[4][4] = {};
#pragma unroll
  for (int ks = 0; ks < 2; ks++) {
    int co = 32 * ks + 8 * q4;
    h16x8 af[4], bfv[4];
#pragma unroll
    for (int i = 0; i < 4; i++) {
      int row = 64 * wy + 16 * i + l15;
      af[i] = *(const h16x8*)((const char*)Al + ((row * 128 + co * 2) ^ ((row & 7) << 4)));
    }
#pragma unroll
    for (int j = 0; j < 4; j++) {
      int row = 64 * wx + 16 * j + l15;
      bfv[j] = *(const h16x8*)((const char*)Bl + ((row * 128 + co * 2) ^ ((row & 7) << 4)));
    }
#pragma unroll
    for (int i = 0; i < 4; i++)
#pragma unroll
      for (int j = 0; j < 4; j++) acc[i][j] = mfma16(af[i], bfv[j], acc[i][j]);
  }
  __syncthreads();  // all LDS reads done before pool reuse
  h16 (*Clds)[136] = (h16(*)[136])pool;
#pragma unroll
  for (int i = 0; i < 4; i++)
#pragma unroll
    for (int j = 0; j < 4; j++)
#pragma unroll
      for (int r = 0; r < 4; r++) {
        int rloc = 64 * wy + 16 * i + q4 * 4 + r;
        int cloc = 64 * wx + 16 * j + l15;
        int gr = rt * 128 + rloc;
        int gj = jt * 128 + cloc;
        float v = acc[i][j][r];
        float o;
        if (!is_sig) o = (gj <= gr) ? v : 0.f;
        else         o = (gj > gr) ? 1.f / (1.f + __expf(-v)) : 0.f;
        Clds[rloc][cloc] = (h16)o;
      }
  __syncthreads();
  int t = threadIdx.x;
  int rloc = t >> 1, half = t & 1;
  h16* dst = out + (size_t)(rt * 128 + rloc) * NN + jt * 128 + 64 * half;
#pragma unroll
  for (int e = 0; e < 8; e++)
    *(h16x8*)(dst + 8 * e) = *(const h16x8*)&Clds[rloc][64 * half + 8 * e];
}

// ---------------- scores = Qc_s.Kc^T - silu(term @ sig^T), causal mask ----------------
// m97-style: 128x128 tile, 4 waves, BK=64 single-buffered (32KB -> 4 blocks/CU),
// 2-barrier loop, XOR-swizzled LDS both sides, bijective XCD swizzle, It-descending.
__global__ __launch_bounds__(256) void k_scores(const h16* __restrict__ qkv,
                                                const h16* __restrict__ term, const h16* __restrict__ sig,
                                                h16* __restrict__ scores, int bh0) {
  __shared__ h16 pool[128 * 136];  // loop: Al+Bl (32KB); epilogue: Clds[128][136]
  h16* Al = pool;
  h16* Bl = pool + 128 * 64;
  int nwg = gridDim.x;
  int q = nwg >> 3, rmd = nwg & 7;
  int xcd = blockIdx.x & 7, idx = blockIdx.x >> 3;
  int wg = (xcd < rmd) ? xcd * (q + 1) + idx : rmd * (q + 1) + (xcd - rmd) * q + idx;
  int lz = wg / 136, r = wg % 136;
  int It = 15, base = 0;               // descending: longest K-loops first
  while (r - base >= It + 1) { base += It + 1; --It; }
  int Kt = r - base;                   // Kt <= It
  int bh = bh0 + lz;
  const h16* Ab = term + (size_t)lz * NN * NN + (size_t)(It * 128) * NN;
  const h16* Bb = sig + (size_t)lz * NN * NN + (size_t)(Kt * 128) * NN;
  int i0 = It * 128, k0 = Kt * 128;
  int lane = threadIdx.x & 63, wv = threadIdx.x >> 6;
  int wy = wv >> 1, wx = wv & 1;
  int l15 = lane & 15, q4 = lane >> 4;
  int lr = lane >> 3, lchunk = lane & 7;
  f32x4 acc[4][4] = {};
  for (int js = k0; js < i0 + 128; js += 64) {
#pragma unroll
    for (int inst = 0; inst < 4; inst++) {
      int rbase = 32 * wv + 8 * inst;
      int row = rbase + lr;
      int sc_ = (lchunk ^ (row & 7)) * 8;
      glds16(Ab + (size_t)row * NN + js + sc_, Al + rbase * 64);
      glds16(Bb + (size_t)row * NN + js + sc_, Bl + rbase * 64);
    }
    __syncthreads();
#pragma unroll
    for (int ks = 0; ks < 2; ks++) {
      int co = 32 * ks + 8 * q4;
      h16x8 af[4], bfv[4];
#pragma unroll
      for (int i = 0; i < 4; i++) {
        int row = 64 * wy + 16 * i + l15;
        af[i] = *(const h16x8*)((const char*)Al + ((row * 128 + co * 2) ^ ((row & 7) << 4)));
      }
#pragma unroll
      for (int j = 0; j < 4; j++) {
        int row = 64 * wx + 16 * j + l15;
        bfv[j] = *(const h16x8*)((const char*)Bl + ((row * 128 + co * 2) ^ ((row & 7) << 4)));
      }
#pragma unroll
      for (int i = 0; i < 4; i++)
#pragma unroll
        for (int j = 0; j < 4; j++) acc[i][j] = mfma16(af[i], bfv[j], acc[i][j]);
    }
    __syncthreads();
  }
  // acc = -silu(S_u)
#pragma unroll
  for (int i = 0; i < 4; i++)
#pragma unroll
    for (int j = 0; j < 4; j++)
#pragma unroll
      for (int rr = 0; rr < 4; rr++) {
        float xv = acc[i][j][rr];
        acc[i][j][rr] = -xv / (1.f + __expf(-xv));
      }
  // acc += Qc_s . Kc^T
  const h16* Q  = qkv + ((size_t)3 * BH + bh) * NN * DH;
  const h16* Kc = qkv + ((size_t)4 * BH + bh) * NN * DH;
#pragma unroll
  for (int d2 = 0; d2 < 2; d2++) {
    int kb = 32 * d2 + 8 * q4;
    h16x8 af[4], bfv[4];
#pragma unroll
    for (int i = 0; i < 4; i++)
      af[i] = *(const h16x8*)(Q + (size_t)(i0 + 64 * wy + 16 * i + l15) * DH + kb);
#pragma unroll
    for (int j = 0; j < 4; j++)
      bfv[j] = *(const h16x8*)(Kc + (size_t)(k0 + 64 * wx + 16 * j + l15) * DH + kb);
#pragma unroll
    for (int i = 0; i < 4; i++)
#pragma unroll
      for (int j = 0; j < 4; j++) acc[i][j] = mfma16(af[i], bfv[j], acc[i][j]);
  }
  // epilogue: mask, stage in LDS (pool reuse), coalesced writes
  h16 (*Clds)[136] = (h16(*)[136])pool;
#pragma unroll
  for (int i = 0; i < 4; i++)
#pragma unroll
    for (int j = 0; j < 4; j++)
#pragma unroll
      for (int rr = 0; rr < 4; rr++) {
        int rloc = 64 * wy + 16 * i + q4 * 4 + rr;
        int cloc = 64 * wx + 16 * j + l15;
        float v = (k0 + cloc <= i0 + rloc) ? acc[i][j][rr] : -__builtin_inff();
        Clds[rloc][cloc] = (h16)v;
      }
  __syncthreads();
  h16* sc = scores + (size_t)lz * NN * NN;
  int t = threadIdx.x;
  int rloc = t >> 1, half = t & 1;
  h16* dst = sc + (size_t)(i0 + rloc) * NN + k0 + 64 * half;
#pragma unroll
  for (int e = 0; e < 8; e++)
    *(h16x8*)(dst + 8 * e) = *(const h16x8*)&Clds[rloc][64 * half + 8 * e];
}

// ---------------- row softmax (in place, fp16 scores -> fp16 probs) ----------------
__global__ __launch_bounds__(256) void k_softmax(h16* __restrict__ sbuf) {
  int lane = threadIdx.x & 63, wv = threadIdx.x >> 6;
  int i = blockIdx.x * 4 + wv;
  int lz = blockIdx.y;
  h16* srow = sbuf + ((size_t)lz * NN + i) * NN;
  int kend = ((i >> 7) + 1) << 7;  // 128-aligned end of processed region
  float v[32];
  float m = -__builtin_inff();
#pragma unroll
  for (int it = 0; it < 4; it++) {
    int base = it * 512 + lane * 8;
    if (base < kend) {
      h16x8 raw = *(const h16x8*)(srow + base);
#pragma unroll
      for (int e = 0; e < 8; e++) {
        float xv = (float)raw[e];
        v[it * 8 + e] = xv;
        m = fmaxf(m, xv);
      }
    } else {
#pragma unroll
      for (int e = 0; e < 8; e++) v[it * 8 + e] = -__builtin_inff();
    }
  }
#pragma unroll
  for (int off = 32; off > 0; off >>= 1) m = fmaxf(m, __shfl_xor(m, off));
  float s = 0.f;
#pragma unroll
  for (int t = 0; t < 32; t++) {
    float e = __expf(v[t] - m);
    v[t] = e;
    s += e;
  }
#pragma unroll
  for (int off = 32; off > 0; off >>= 1) s += __shfl_xor(s, off);
  float inv = 1.f / s;
#pragma unroll
  for (int it = 0; it < 4; it++) {
    int base = it * 512 + lane * 8;
    if (base < kend) {
      h16x8 o;
#pragma unroll
      for (int e = 0; e < 8; e++) o[e] = (h16)(v[it * 8 + e] * inv);
      *(h16x8*)(srow + base) = o;
    }
  }
}

// ---------------- PV: attn_out = P @ Vc (64-row tiles) ----------------
__global__ __launch_bounds__(256) void k_pv(const h16* __restrict__ P, const h16* __restrict__ vcT,
                                            h16* __restrict__ attn, int bh0) {
  int It64 = blockIdx.x, lz = blockIdx.z, bh = bh0 + lz;
  int lane = threadIdx.x & 63, wv = threadIdx.x >> 6;
  const h16* Pb = P + (size_t)lz * NN * NN;
  const h16* VT = vcT + (size_t)bh * DH * NN;  // [d][n]
  int i0 = It64 * 64;
  int kend = ((It64 >> 1) + 1) << 7;  // 128-aligned end of causal row extent
  f32x4 acc[4] = {};
  int kb = 8 * (lane >> 4);
  const h16* prow = Pb + (size_t)(i0 + 16 * wv + (lane & 15)) * NN;
  for (int kk = 0; kk < kend; kk += 32) {
    h16x8 af = *(const h16x8*)(prow + kk + kb);
#pragma unroll
    for (int c = 0; c < 4; c++) {
      h16x8 bfv = *(const h16x8*)(VT + (size_t)(16 * c + (lane & 15)) * NN + kk + kb);
      acc[c] = mfma16(af, bfv, acc[c]);
    }
  }
  int hh = bh & 7, b = bh >> 3;
  int ri = i0 + 16 * wv + (lane >> 4) * 4;
  int cd0 = lane & 15;
#pragma unroll
  for (int c = 0; c < 4; c++)
#pragma unroll
    for (int r = 0; r < 4; r++) {
      int gi = ri + r, gd = cd0 + 16 * c;
      attn[((size_t)b * NN + gi) * DIM + hh * DH + gd] = (h16)acc[c][r];
    }
}

// ---------------- output projection (fp32 out) ----------------
__global__ __launch_bounds__(256) void k_outproj(const h16* __restrict__ attn, const h16* __restrict__ Wt,
                                                 float* __restrict__ out) {
  int m0 = blockIdx.x * 64, o0 = blockIdx.y * 64;
  int lane = threadIdx.x & 63, wv = threadIdx.x >> 6;
  int kb = 8 * (lane >> 4);
  f32x4 acc[4] = {};
  const h16* ap = attn + (size_t)(m0 + 16 * wv + (lane & 15)) * DIM + kb;
  const h16* bp = Wt + (size_t)(o0 + (lane & 15)) * DIM + kb;
  for (int k0 = 0; k0 < DIM; k0 += 32) {
    h16x8 af = *(const h16x8*)(ap + k0);
#pragma unroll
    for (int t = 0; t < 4; t++) {
      h16x8 bfv = *(const h16x8*)(bp + (size_t)(16 * t) * DIM + k0);
      acc[t] = mfma16(af, bfv, acc[t]);
    }
  }
  int ri = m0 + 16 * wv + (lane >> 4) * 4;
  int c0 = o0 + (lane & 15);
#pragma unroll
  for (int t = 0; t < 4; t++)
#pragma unroll
    for (int r = 0; r < 4; r++) out[(size_t)(ri + r) * DIM + c0 + 16 * t] = acc[t][r];
}

// ---------------- launch ----------------

extern "C" void kernel_launch(void* const* d_in, const int* in_sizes, int n_in,
                              void* d_out, int out_size, void* d_ws, size_t ws_size,
                              hipStream_t stream) {
  const float* x = (const float*)d_in[0];
  WPtrs wp;
  for (int i = 0; i < 7; i++) wp.w[i] = (const float*)d_in[1 + i];

  char* p = (char*)d_ws;
  auto alloc = [&](size_t bytes) {
    void* r = (void*)p;
    p += (bytes + 255) & ~(size_t)255;
    return r;
  };
  h16* xh   = (h16*)alloc((size_t)4096 * DIM * 2);            // 4 MB
  h16* wt   = (h16*)alloc((size_t)7 * DIM * DIM * 2);         // 3.5 MB
  h16* qkv  = (h16*)alloc((size_t)6 * BH * NN * DH * 2);      // 24 MB
  h16* vcT  = (h16*)alloc((size_t)BH * DH * NN * 2);          // 4 MB
  h16* attn = (h16*)alloc((size_t)4096 * DIM * 2);            // 4 MB
  size_t used = (size_t)(p - (char*)d_ws);
  size_t per_bh = (size_t)NN * NN * 2;                        // 8 MB
  size_t avail = ws_size > used ? ws_size - used : 0;
  int CH = 16;
  while (CH > 1 && (size_t)CH * per_bh * 3 > avail) CH >>= 1;
  h16* term   = (h16*)alloc((size_t)CH * per_bh);
  h16* sig    = (h16*)alloc((size_t)CH * per_bh);
  h16* scores = (h16*)alloc((size_t)CH * per_bh);

  k_pack_x<<<dim3(2048), dim3(256), 0, stream>>>(x, xh);
  k_pack_w<<<dim3(8, 8, 7), dim3(256), 0, stream>>>(wp, wt);
  k_proj<<<dim3(32, 24), dim3(256), 0, stream>>>(xh, wt, qkv, vcT);

  for (int c0 = 0; c0 < BH; c0 += CH) {
    k_termsig<<<dim3(152, 2, CH), dim3(256), 0, stream>>>(qkv, term, sig, c0);
    k_scores<<<dim3(136 * CH), dim3(256), 0, stream>>>(qkv, term, sig, scores, c0);
    k_softmax<<<dim3(NN / 4, CH), dim3(256), 0, stream>>>(scores);
    k_pv<<<dim3(NN / 64, 1, CH), dim3(256), 0, stream>>>(scores, vcT, attn, c0);
  }

  k_outproj<<<dim3(64, 8), dim3(256), 0, stream>>>(attn, wt + (size_t)6 * DIM * DIM, (float*)d_out);
}

// Round 8
// 355.102 us; speedup vs baseline: 1.3427x; 1.0442x over previous
//
#include <hip/hip_runtime.h>
#include <hip/hip_bf16.h>

typedef _Float16 h16;
typedef _Float16 h16x8 __attribute__((ext_vector_type(8)));
typedef float f32x4 __attribute__((ext_vector_type(4)));

#define DEVI static __device__ __forceinline__

constexpr int NN = 2048;     // sequence length
constexpr int DIM = 512;
constexpr int NH = 8;
constexpr int DH = 64;
constexpr int BH = 16;       // B * H
constexpr float FSCALE = 0.125f;  // DH^-0.5

DEVI f32x4 mfma16(h16x8 a, h16x8 b, f32x4 c) {
  return __builtin_amdgcn_mfma_f32_16x16x32_f16(a, b, c, 0, 0, 0);
}

DEVI void glds16(const void* g, void* l) {
  __builtin_amdgcn_global_load_lds(
      (const __attribute__((address_space(1))) unsigned int*)g,
      (__attribute__((address_space(3))) unsigned int*)l, 16, 0, 0);
}

DEVI void tri_decode(int p, int& a, int& b) {
  a = (int)((sqrtf(8.f * p + 1.f) - 1.f) * 0.5f);
  while ((a + 1) * (a + 2) / 2 <= p) ++a;
  while (a * (a + 1) / 2 > p) --a;
  b = p - a * (a + 1) / 2;
}

// ---------------- pack kernels ----------------

__global__ __launch_bounds__(256) void k_pack_x(const float* __restrict__ x, h16* __restrict__ xh) {
  int i = (blockIdx.x * 256 + threadIdx.x) * 4;
  float4 v = *(const float4*)(x + i);
  union { h16 h[4]; uint2 u; } pk;
  pk.h[0] = (h16)v.x; pk.h[1] = (h16)v.y; pk.h[2] = (h16)v.z; pk.h[3] = (h16)v.w;
  *(uint2*)(xh + i) = pk.u;
}

struct WPtrs { const float* w[7]; };

// transpose+cast each 512x512 weight: wt[o][k] = W[k][o]
__global__ __launch_bounds__(256) void k_pack_w(WPtrs wp, h16* __restrict__ wt) {
  const float* W = wp.w[blockIdx.z];
  h16* out = wt + (size_t)blockIdx.z * DIM * DIM;
  __shared__ h16 t[64][65];
  int k0 = blockIdx.x * 64, o0 = blockIdx.y * 64;
  int c = threadIdx.x & 63, r4 = threadIdx.x >> 6;
#pragma unroll
  for (int rr = 0; rr < 64; rr += 4) {
    int r = rr + r4;
    t[r][c] = (h16)W[(size_t)(k0 + r) * DIM + o0 + c];
  }
  __syncthreads();
#pragma unroll
  for (int rr = 0; rr < 64; rr += 4) {
    int r = rr + r4;
    out[(size_t)(o0 + r) * DIM + k0 + c] = t[c][r];
  }
}

// ---------------- fused QKV projection ----------------
__global__ __launch_bounds__(256) void k_proj(const h16* __restrict__ xh, const h16* __restrict__ wt,
                                              h16* __restrict__ qkv, h16* __restrict__ vcT) {
  __shared__ h16 pool[128 * 136];
  h16* Al = pool;
  h16* Bl = pool + 128 * 64;
  int m0 = blockIdx.x * 128, o0 = blockIdx.y * 128;
  int lane = threadIdx.x & 63, wv = threadIdx.x >> 6;
  int wy = wv >> 1, wx = wv & 1;
  int srow = 32 * wv;
  int lr = lane >> 3, lc = 8 * (lane & 7);
  f32x4 acc[4][4] = {};
  for (int ks0 = 0; ks0 < DIM; ks0 += 64) {
#pragma unroll
    for (int inst = 0; inst < 4; inst++) {
      int r = srow + 8 * inst;
      glds16(xh + (size_t)(m0 + r + lr) * DIM + ks0 + lc, Al + r * 64);
      glds16(wt + (size_t)(o0 + r + lr) * DIM + ks0 + lc, Bl + r * 64);
    }
    __syncthreads();
#pragma unroll
    for (int ks = 0; ks < 2; ks++) {
      h16x8 af[4], bfv[4];
      int co = 32 * ks + 8 * (lane >> 4);
#pragma unroll
      for (int i = 0; i < 4; i++) af[i] = *(const h16x8*)(Al + (64 * wy + 16 * i + (lane & 15)) * 64 + co);
#pragma unroll
      for (int j = 0; j < 4; j++) bfv[j] = *(const h16x8*)(Bl + (64 * wx + 16 * j + (lane & 15)) * 64 + co);
#pragma unroll
      for (int i = 0; i < 4; i++)
#pragma unroll
        for (int j = 0; j < 4; j++) acc[i][j] = mfma16(af[i], bfv[j], acc[i][j]);
    }
    __syncthreads();
  }
  int widx = o0 >> 9;
  float scl = (widx == 0 || widx == 3) ? FSCALE : 1.0f;
  h16 (*Clds)[136] = (h16(*)[136])pool;
#pragma unroll
  for (int i = 0; i < 4; i++)
#pragma unroll
    for (int j = 0; j < 4; j++)
#pragma unroll
      for (int r = 0; r < 4; r++) {
        int rloc = 64 * wy + 16 * i + (lane >> 4) * 4 + r;
        int cloc = 64 * wx + 16 * j + (lane & 15);
        Clds[rloc][cloc] = (h16)(acc[i][j][r] * scl);
      }
  __syncthreads();
  int t = threadIdx.x;
  {
    int rloc = t >> 1, half = t & 1;
    int gi = m0 + rloc;
    int b = gi >> 11, n = gi & 2047;
    int og = o0 + 64 * half;
    int h = (og >> 6) & 7;
    h16* dst = qkv + (((size_t)widx * BH + b * NH + h) * NN + n) * DH;
#pragma unroll
    for (int e = 0; e < 8; e++)
      *(h16x8*)(dst + 8 * e) = *(const h16x8*)&Clds[rloc][64 * half + 8 * e];
  }
  if (widx == 5) {
    int c = t & 127, rq = t >> 7;
    int og = o0 + c;
    int h = (og >> 6) & 7, d = og & 63;
    int b = m0 >> 11, nb = (m0 & 2047) + rq * 64;
    h16* dst = vcT + ((size_t)(b * NH + h) * DH + d) * NN + nb;
#pragma unroll
    for (int g = 0; g < 8; g++) {
      h16x8 w;
#pragma unroll
      for (int e = 0; e < 8; e++) w[e] = Clds[rq * 64 + 8 * g + e][c];
      *(h16x8*)(dst + 8 * g) = w;
    }
  }
}

// ---------------- term1 & sigmoid matrices (LDS-staged operands) ----------------
__global__ __launch_bounds__(256) void k_termsig(const h16* __restrict__ qkv,
                                                 h16* __restrict__ term, h16* __restrict__ sig, int bh0) {
  int pidx = blockIdx.x;
  bool is_sig = blockIdx.y != 0;
  int lz = blockIdx.z, bh = bh0 + lz;
  int rt, jt;
  if (pidx >= 144) {
    if (!is_sig) return;
    int mm = pidx - 144;
    rt = 2 * mm + 1; jt = 2 * mm;
  } else if (pidx >= 136) {
    int mm = pidx - 136;
    rt = 2 * mm; jt = 2 * mm + 1;
  } else {
    int a, bq;
    tri_decode(pidx, a, bq);
    rt = is_sig ? bq : a;
    jt = is_sig ? a : bq;
  }
  const h16* A  = qkv + ((size_t)(is_sig ? 0 : 3) * BH + bh) * NN * DH;
  const h16* Bv = qkv + ((size_t)(is_sig ? 1 : 2) * BH + bh) * NN * DH;
  h16* out = (is_sig ? sig : term) + (size_t)lz * NN * NN;
  int lane = threadIdx.x & 63, wv = threadIdx.x >> 6;
  int wy = wv >> 1, wx = wv & 1;
  int l15 = lane & 15, q4 = lane >> 4;
  int lr = lane >> 3, lchunk = lane & 7;
  __shared__ h16 pool[128 * 136];
  h16* Al = pool;
  h16* Bl = pool + 128 * 64;
#pragma unroll
  for (int inst = 0; inst < 4; inst++) {
    int rbase = 32 * wv + 8 * inst;
    int row = rbase + lr;
    int sc_ = (lchunk ^ (row & 7)) * 8;
    glds16(A + (size_t)(rt * 128 + row) * DH + sc_, Al + rbase * 64);
    glds16(Bv + (size_t)(jt * 128 + row) * DH + sc_, Bl + rbase * 64);
  }
  __syncthreads();
  f32x4 acc[4][4] = {};
#pragma unroll
  for (int ks = 0; ks < 2; ks++) {
    int co = 32 * ks + 8 * q4;
    h16x8 af[4], bfv[4];
#pragma unroll
    for (int i = 0; i < 4; i++) {
      int row = 64 * wy + 16 * i + l15;
      af[i] = *(const h16x8*)((const char*)Al + ((row * 128 + co * 2) ^ ((row & 7) << 4)));
    }
#pragma unroll
    for (int j = 0; j < 4; j++) {
      int row = 64 * wx + 16 * j + l15;
      bfv[j] = *(const h16x8*)((const char*)Bl + ((row * 128 + co * 2) ^ ((row & 7) << 4)));
    }
#pragma unroll
    for (int i = 0; i < 4; i++)
#pragma unroll
      for (int j = 0; j < 4; j++) acc[i][j] = mfma16(af[i], bfv[j], acc[i][j]);
  }
  __syncthreads();
  h16 (*Clds)[136] = (h16(*)[136])pool;
#pragma unroll
  for (int i = 0; i < 4; i++)
#pragma unroll
    for (int j = 0; j < 4; j++)
#pragma unroll
      for (int r = 0; r < 4; r++) {
        int rloc = 64 * wy + 16 * i + q4 * 4 + r;
        int cloc = 64 * wx + 16 * j + l15;
        int gr = rt * 128 + rloc;
        int gj = jt * 128 + cloc;
        float v = acc[i][j][r];
        float o;
        if (!is_sig) o = (gj <= gr) ? v : 0.f;
        else         o = (gj > gr) ? 1.f / (1.f + __expf(-v)) : 0.f;
        Clds[rloc][cloc] = (h16)o;
      }
  __syncthreads();
  int t = threadIdx.x;
  int rloc = t >> 1, half = t & 1;
  h16* dst = out + (size_t)(rt * 128 + rloc) * NN + jt * 128 + 64 * half;
#pragma unroll
  for (int e = 0; e < 8; e++)
    *(h16x8*)(dst + 8 * e) = *(const h16x8*)&Clds[rloc][64 * half + 8 * e];
}

// ---------------- scores + per-tile softmax partials ----------------
// scores = Qc_s.Kc^T - silu(term @ sig^T) with causal mask (raw, unnormalized).
// Also emits per-(row, Kt-tile) partials: pmax = row max, psum = sum exp(s - pmax).
__global__ __launch_bounds__(256) void k_scores(const h16* __restrict__ qkv,
                                                const h16* __restrict__ term, const h16* __restrict__ sig,
                                                h16* __restrict__ scores,
                                                float* __restrict__ pmax, float* __restrict__ psum, int bh0) {
  __shared__ h16 pool[128 * 136];  // loop: Al+Bl (32KB); epilogue: Clds[128][136]
  h16* Al = pool;
  h16* Bl = pool + 128 * 64;
  int nwg = gridDim.x;
  int q = nwg >> 3, rmd = nwg & 7;
  int xcd = blockIdx.x & 7, idx = blockIdx.x >> 3;
  int wg = (xcd < rmd) ? xcd * (q + 1) + idx : rmd * (q + 1) + (xcd - rmd) * q + idx;
  int lz = wg / 136, r = wg % 136;
  int It = 15, base = 0;               // descending: longest K-loops first
  while (r - base >= It + 1) { base += It + 1; --It; }
  int Kt = r - base;                   // Kt <= It
  int bh = bh0 + lz;
  const h16* Ab = term + (size_t)lz * NN * NN + (size_t)(It * 128) * NN;
  const h16* Bb = sig + (size_t)lz * NN * NN + (size_t)(Kt * 128) * NN;
  int i0 = It * 128, k0 = Kt * 128;
  int lane = threadIdx.x & 63, wv = threadIdx.x >> 6;
  int wy = wv >> 1, wx = wv & 1;
  int l15 = lane & 15, q4 = lane >> 4;
  int lr = lane >> 3, lchunk = lane & 7;
  f32x4 acc[4][4] = {};
  for (int js = k0; js < i0 + 128; js += 64) {
#pragma unroll
    for (int inst = 0; inst < 4; inst++) {
      int rbase = 32 * wv + 8 * inst;
      int row = rbase + lr;
      int sc_ = (lchunk ^ (row & 7)) * 8;
      glds16(Ab + (size_t)row * NN + js + sc_, Al + rbase * 64);
      glds16(Bb + (size_t)row * NN + js + sc_, Bl + rbase * 64);
    }
    __syncthreads();
#pragma unroll
    for (int ks = 0; ks < 2; ks++) {
      int co = 32 * ks + 8 * q4;
      h16x8 af[4], bfv[4];
#pragma unroll
      for (int i = 0; i < 4; i++) {
        int row = 64 * wy + 16 * i + l15;
        af[i] = *(const h16x8*)((const char*)Al + ((row * 128 + co * 2) ^ ((row & 7) << 4)));
      }
#pragma unroll
      for (int j = 0; j < 4; j++) {
        int row = 64 * wx + 16 * j + l15;
        bfv[j] = *(const h16x8*)((const char*)Bl + ((row * 128 + co * 2) ^ ((row & 7) << 4)));
      }
#pragma unroll
      for (int i = 0; i < 4; i++)
#pragma unroll
        for (int j = 0; j < 4; j++) acc[i][j] = mfma16(af[i], bfv[j], acc[i][j]);
    }
    __syncthreads();
  }
  // acc = -silu(S_u)
#pragma unroll
  for (int i = 0; i < 4; i++)
#pragma unroll
    for (int j = 0; j < 4; j++)
#pragma unroll
      for (int rr = 0; rr < 4; rr++) {
        float xv = acc[i][j][rr];
        acc[i][j][rr] = -xv / (1.f + __expf(-xv));
      }
  // acc += Qc_s . Kc^T
  const h16* Q  = qkv + ((size_t)3 * BH + bh) * NN * DH;
  const h16* Kc = qkv + ((size_t)4 * BH + bh) * NN * DH;
#pragma unroll
  for (int d2 = 0; d2 < 2; d2++) {
    int kb = 32 * d2 + 8 * q4;
    h16x8 af[4], bfv[4];
#pragma unroll
    for (int i = 0; i < 4; i++)
      af[i] = *(const h16x8*)(Q + (size_t)(i0 + 64 * wy + 16 * i + l15) * DH + kb);
#pragma unroll
    for (int j = 0; j < 4; j++)
      bfv[j] = *(const h16x8*)(Kc + (size_t)(k0 + 64 * wx + 16 * j + l15) * DH + kb);
#pragma unroll
    for (int i = 0; i < 4; i++)
#pragma unroll
      for (int j = 0; j < 4; j++) acc[i][j] = mfma16(af[i], bfv[j], acc[i][j]);
  }
  // epilogue: mask, stage in LDS (pool reuse)
  h16 (*Clds)[136] = (h16(*)[136])pool;
#pragma unroll
  for (int i = 0; i < 4; i++)
#pragma unroll
    for (int j = 0; j < 4; j++)
#pragma unroll
      for (int rr = 0; rr < 4; rr++) {
        int rloc = 64 * wy + 16 * i + q4 * 4 + rr;
        int cloc = 64 * wx + 16 * j + l15;
        float v = (k0 + cloc <= i0 + rloc) ? acc[i][j][rr] : -__builtin_inff();
        Clds[rloc][cloc] = (h16)v;
      }
  __syncthreads();
  // fused: coalesced store + online per-row max/sumexp over this tile's 128 cols
  h16* sc = scores + (size_t)lz * NN * NN;
  int t = threadIdx.x;
  int rloc = t >> 1, half = t & 1;
  h16* dst = sc + (size_t)(i0 + rloc) * NN + k0 + 64 * half;
  float mx = -1e30f, ls = 0.f;
#pragma unroll
  for (int e = 0; e < 8; e++) {
    h16x8 v8 = *(const h16x8*)&Clds[rloc][64 * half + 8 * e];
    *(h16x8*)(dst + 8 * e) = v8;
    float cm = mx;
#pragma unroll
    for (int qe = 0; qe < 8; qe++) cm = fmaxf(cm, (float)v8[qe]);
    ls *= __expf(mx - cm);
#pragma unroll
    for (int qe = 0; qe < 8; qe++) ls += __expf((float)v8[qe] - cm);
    mx = cm;
  }
  float om = __shfl_xor(mx, 1), ol = __shfl_xor(ls, 1);
  float M = fmaxf(mx, om);
  float L = ls * __expf(mx - M) + ol * __expf(om - M);
  if (half == 0) {
    size_t pi = ((size_t)lz * 16 + Kt) * NN + i0 + rloc;
    pmax[pi] = M;
    psum[pi] = L;
  }
}

// ---------------- PV: attn_out = softmax(scores) @ Vc, normalization on the fly ----------------
__global__ __launch_bounds__(256) void k_pv(const h16* __restrict__ P, const h16* __restrict__ vcT,
                                            const float* __restrict__ pmax, const float* __restrict__ psum,
                                            h16* __restrict__ attn, int bh0) {
  int It64 = blockIdx.x, lz = blockIdx.z, bh = bh0 + lz;
  int lane = threadIdx.x & 63, wv = threadIdx.x >> 6;
  int l15 = lane & 15, q4 = lane >> 4, kb = 8 * q4;
  const h16* Pb = P + (size_t)lz * NN * NN;
  const h16* VT = vcT + (size_t)bh * DH * NN;  // [d][n]
  int i0 = It64 * 64;
  int stripe = It64 >> 1;
  int ntk = stripe + 1;
  int kend = ntk << 7;
  int myrow = i0 + 16 * wv + l15;
  // merge per-tile partials -> global row max M and denom L
  const float* pm = pmax + (size_t)lz * 16 * NN + myrow;
  const float* pl = psum + (size_t)lz * 16 * NN + myrow;
  float M = -1e30f;
  for (int tk = 0; tk < ntk; tk++) M = fmaxf(M, pm[(size_t)tk * NN]);
  float L = 0.f;
  for (int tk = 0; tk < ntk; tk++) L += pl[(size_t)tk * NN] * __expf(pm[(size_t)tk * NN] - M);
  float invL = 1.f / L;
  // single pass: normalize + PV
  f32x4 acc[4] = {};
  const h16* prow = Pb + (size_t)myrow * NN;
  for (int kk = 0; kk < kend; kk += 32) {
    h16x8 raw = *(const h16x8*)(prow + kk + kb);
    h16x8 af;
#pragma unroll
    for (int e = 0; e < 8; e++) af[e] = (h16)(__expf((float)raw[e] - M) * invL);
#pragma unroll
    for (int c = 0; c < 4; c++) {
      h16x8 bfv = *(const h16x8*)(VT + (size_t)(16 * c + l15) * NN + kk + kb);
      acc[c] = mfma16(af, bfv, acc[c]);
    }
  }
  // stage 64x64 tile in LDS, coalesced write
  __shared__ h16 tl[64][72];
  int ri = 16 * wv + 4 * q4;
#pragma unroll
  for (int c = 0; c < 4; c++)
#pragma unroll
    for (int r = 0; r < 4; r++) tl[ri + r][l15 + 16 * c] = (h16)acc[c][r];
  __syncthreads();
  int t = threadIdx.x;
  int row = t >> 2, cg = (t & 3) * 16;
  int hh = bh & 7, b = bh >> 3;
  h16* dst = attn + ((size_t)b * NN + i0 + row) * DIM + hh * DH + cg;
  *(h16x8*)dst = *(const h16x8*)&tl[row][cg];
  *(h16x8*)(dst + 8) = *(const h16x8*)&tl[row][cg + 8];
}

// ---------------- output projection (fp32 out) ----------------
__global__ __launch_bounds__(256) void k_outproj(const h16* __restrict__ attn, const h16* __restrict__ Wt,
                                                 float* __restrict__ out) {
  int m0 = blockIdx.x * 64, o0 = blockIdx.y * 64;
  int lane = threadIdx.x & 63, wv = threadIdx.x >> 6;
  int kb = 8 * (lane >> 4);
  f32x4 acc[4] = {};
  const h16* ap = attn + (size_t)(m0 + 16 * wv + (lane & 15)) * DIM + kb;
  const h16* bp = Wt + (size_t)(o0 + (lane & 15)) * DIM + kb;
  for (int k0 = 0; k0 < DIM; k0 += 32) {
    h16x8 af = *(const h16x8*)(ap + k0);
#pragma unroll
    for (int t = 0; t < 4; t++) {
      h16x8 bfv = *(const h16x8*)(bp + (size_t)(16 * t) * DIM + k0);
      acc[t] = mfma16(af, bfv, acc[t]);
    }
  }
  int ri = m0 + 16 * wv + (lane >> 4) * 4;
  int c0 = o0 + (lane & 15);
#pragma unroll
  for (int t = 0; t < 4; t++)
#pragma unroll
    for (int r = 0; r < 4; r++) out[(size_t)(ri + r) * DIM + c0 + 16 * t] = acc[t][r];
}

// ---------------- launch ----------------

extern "C" void kernel_launch(void* const* d_in, const int* in_sizes, int n_in,
                              void* d_out, int out_size, void* d_ws, size_t ws_size,
                              hipStream_t stream) {
  const float* x = (const float*)d_in[0];
  WPtrs wp;
  for (int i = 0; i < 7; i++) wp.w[i] = (const float*)d_in[1 + i];

  char* p = (char*)d_ws;
  auto alloc = [&](size_t bytes) {
    void* r = (void*)p;
    p += (bytes + 255) & ~(size_t)255;
    return r;
  };
  h16* xh   = (h16*)alloc((size_t)4096 * DIM * 2);            // 4 MB
  h16* wt   = (h16*)alloc((size_t)7 * DIM * DIM * 2);         // 3.5 MB
  h16* qkv  = (h16*)alloc((size_t)6 * BH * NN * DH * 2);      // 24 MB
  h16* vcT  = (h16*)alloc((size_t)BH * DH * NN * 2);          // 4 MB
  h16* attn = (h16*)alloc((size_t)4096 * DIM * 2);            // 4 MB
  size_t used = (size_t)(p - (char*)d_ws);
  size_t per_bh = (size_t)NN * NN * 2;                        // 8 MB
  size_t avail = ws_size > used ? ws_size - used : 0;
  int CH = 8;  // 8 chunks: term+sig+scores+partials ~196MB fits the 256MB L3
  while (CH > 1 && (size_t)CH * (per_bh * 3 + 16 * NN * 8) > avail) CH >>= 1;
  h16* term   = (h16*)alloc((size_t)CH * per_bh);
  h16* sig    = (h16*)alloc((size_t)CH * per_bh);
  h16* scores = (h16*)alloc((size_t)CH * per_bh);
  float* pmax = (float*)alloc((size_t)CH * 16 * NN * 4);
  float* psum = (float*)alloc((size_t)CH * 16 * NN * 4);

  k_pack_x<<<dim3(2048), dim3(256), 0, stream>>>(x, xh);
  k_pack_w<<<dim3(8, 8, 7), dim3(256), 0, stream>>>(wp, wt);
  k_proj<<<dim3(32, 24), dim3(256), 0, stream>>>(xh, wt, qkv, vcT);

  for (int c0 = 0; c0 < BH; c0 += CH) {
    k_termsig<<<dim3(152, 2, CH), dim3(256), 0, stream>>>(qkv, term, sig, c0);
    k_scores<<<dim3(136 * CH), dim3(256), 0, stream>>>(qkv, term, sig, scores, pmax, psum, c0);
    k_pv<<<dim3(NN / 64, 1, CH), dim3(256), 0, stream>>>(scores, vcT, pmax, psum, attn, c0);
  }

  k_outproj<<<dim3(64, 8), dim3(256), 0, stream>>>(attn, wt + (size_t)6 * DIM * DIM, (float*)d_out);
}

// Round 9
// 328.690 us; speedup vs baseline: 1.4506x; 1.0804x over previous
//
#include <hip/hip_runtime.h>
#include <hip/hip_bf16.h>

typedef _Float16 h16;
typedef _Float16 h16x8 __attribute__((ext_vector_type(8)));
typedef float f32x4 __attribute__((ext_vector_type(4)));

#define DEVI static __device__ __forceinline__

constexpr int NN = 2048;     // sequence length
constexpr int DIM = 512;
constexpr int NH = 8;
constexpr int DH = 64;
constexpr int BH = 16;       // B * H
constexpr float FSCALE = 0.125f;  // DH^-0.5

DEVI f32x4 mfma16(h16x8 a, h16x8 b, f32x4 c) {
  return __builtin_amdgcn_mfma_f32_16x16x32_f16(a, b, c, 0, 0, 0);
}

DEVI void glds16(const void* g, void* l) {
  __builtin_amdgcn_global_load_lds(
      (const __attribute__((address_space(1))) unsigned int*)g,
      (__attribute__((address_space(3))) unsigned int*)l, 16, 0, 0);
}

DEVI void tri_decode(int p, int& a, int& b) {
  a = (int)((sqrtf(8.f * p + 1.f) - 1.f) * 0.5f);
  while ((a + 1) * (a + 2) / 2 <= p) ++a;
  while (a * (a + 1) / 2 > p) --a;
  b = p - a * (a + 1) / 2;
}

// ---------------- pack kernels ----------------

__global__ __launch_bounds__(256) void k_pack_x(const float* __restrict__ x, h16* __restrict__ xh) {
  int i = (blockIdx.x * 256 + threadIdx.x) * 4;
  float4 v = *(const float4*)(x + i);
  union { h16 h[4]; uint2 u; } pk;
  pk.h[0] = (h16)v.x; pk.h[1] = (h16)v.y; pk.h[2] = (h16)v.z; pk.h[3] = (h16)v.w;
  *(uint2*)(xh + i) = pk.u;
}

struct WPtrs { const float* w[7]; };

// transpose+cast each 512x512 weight: wt[o][k] = W[k][o]
__global__ __launch_bounds__(256) void k_pack_w(WPtrs wp, h16* __restrict__ wt) {
  const float* W = wp.w[blockIdx.z];
  h16* out = wt + (size_t)blockIdx.z * DIM * DIM;
  __shared__ h16 t[64][65];
  int k0 = blockIdx.x * 64, o0 = blockIdx.y * 64;
  int c = threadIdx.x & 63, r4 = threadIdx.x >> 6;
#pragma unroll
  for (int rr = 0; rr < 64; rr += 4) {
    int r = rr + r4;
    t[r][c] = (h16)W[(size_t)(k0 + r) * DIM + o0 + c];
  }
  __syncthreads();
#pragma unroll
  for (int rr = 0; rr < 64; rr += 4) {
    int r = rr + r4;
    out[(size_t)(o0 + r) * DIM + k0 + c] = t[c][r];
  }
}

// ---------------- fused QKV projection ----------------
__global__ __launch_bounds__(256) void k_proj(const h16* __restrict__ xh, const h16* __restrict__ wt,
                                              h16* __restrict__ qkv, h16* __restrict__ vcT) {
  __shared__ h16 pool[128 * 136];
  h16* Al = pool;
  h16* Bl = pool + 128 * 64;
  int m0 = blockIdx.x * 128, o0 = blockIdx.y * 128;
  int lane = threadIdx.x & 63, wv = threadIdx.x >> 6;
  int wy = wv >> 1, wx = wv & 1;
  int srow = 32 * wv;
  int lr = lane >> 3, lc = 8 * (lane & 7);
  f32x4 acc[4][4] = {};
  for (int ks0 = 0; ks0 < DIM; ks0 += 64) {
#pragma unroll
    for (int inst = 0; inst < 4; inst++) {
      int r = srow + 8 * inst;
      glds16(xh + (size_t)(m0 + r + lr) * DIM + ks0 + lc, Al + r * 64);
      glds16(wt + (size_t)(o0 + r + lr) * DIM + ks0 + lc, Bl + r * 64);
    }
    __syncthreads();
#pragma unroll
    for (int ks = 0; ks < 2; ks++) {
      h16x8 af[4], bfv[4];
      int co = 32 * ks + 8 * (lane >> 4);
#pragma unroll
      for (int i = 0; i < 4; i++) af[i] = *(const h16x8*)(Al + (64 * wy + 16 * i + (lane & 15)) * 64 + co);
#pragma unroll
      for (int j = 0; j < 4; j++) bfv[j] = *(const h16x8*)(Bl + (64 * wx + 16 * j + (lane & 15)) * 64 + co);
#pragma unroll
      for (int i = 0; i < 4; i++)
#pragma unroll
        for (int j = 0; j < 4; j++) acc[i][j] = mfma16(af[i], bfv[j], acc[i][j]);
    }
    __syncthreads();
  }
  int widx = o0 >> 9;
  float scl = (widx == 0 || widx == 3) ? FSCALE : 1.0f;
  h16 (*Clds)[136] = (h16(*)[136])pool;
#pragma unroll
  for (int i = 0; i < 4; i++)
#pragma unroll
    for (int j = 0; j < 4; j++)
#pragma unroll
      for (int r = 0; r < 4; r++) {
        int rloc = 64 * wy + 16 * i + (lane >> 4) * 4 + r;
        int cloc = 64 * wx + 16 * j + (lane & 15);
        Clds[rloc][cloc] = (h16)(acc[i][j][r] * scl);
      }
  __syncthreads();
  int t = threadIdx.x;
  {
    int rloc = t >> 1, half = t & 1;
    int gi = m0 + rloc;
    int b = gi >> 11, n = gi & 2047;
    int og = o0 + 64 * half;
    int h = (og >> 6) & 7;
    h16* dst = qkv + (((size_t)widx * BH + b * NH + h) * NN + n) * DH;
#pragma unroll
    for (int e = 0; e < 8; e++)
      *(h16x8*)(dst + 8 * e) = *(const h16x8*)&Clds[rloc][64 * half + 8 * e];
  }
  if (widx == 5) {
    int c = t & 127, rq = t >> 7;
    int og = o0 + c;
    int h = (og >> 6) & 7, d = og & 63;
    int b = m0 >> 11, nb = (m0 & 2047) + rq * 64;
    h16* dst = vcT + ((size_t)(b * NH + h) * DH + d) * NN + nb;
#pragma unroll
    for (int g = 0; g < 8; g++) {
      h16x8 w;
#pragma unroll
      for (int e = 0; e < 8; e++) w[e] = Clds[rq * 64 + 8 * g + e][c];
      *(h16x8*)(dst + 8 * g) = w;
    }
  }
}

// ---------------- term1 & sigmoid matrices (LDS-staged operands) ----------------
__global__ __launch_bounds__(256) void k_termsig(const h16* __restrict__ qkv,
                                                 h16* __restrict__ term, h16* __restrict__ sig, int bh0) {
  int pidx = blockIdx.x;
  bool is_sig = blockIdx.y != 0;
  int lz = blockIdx.z, bh = bh0 + lz;
  int rt, jt;
  if (pidx >= 144) {
    if (!is_sig) return;
    int mm = pidx - 144;
    rt = 2 * mm + 1; jt = 2 * mm;
  } else if (pidx >= 136) {
    int mm = pidx - 136;
    rt = 2 * mm; jt = 2 * mm + 1;
  } else {
    int a, bq;
    tri_decode(pidx, a, bq);
    rt = is_sig ? bq : a;
    jt = is_sig ? a : bq;
  }
  const h16* A  = qkv + ((size_t)(is_sig ? 0 : 3) * BH + bh) * NN * DH;
  const h16* Bv = qkv + ((size_t)(is_sig ? 1 : 2) * BH + bh) * NN * DH;
  h16* out = (is_sig ? sig : term) + (size_t)lz * NN * NN;
  int lane = threadIdx.x & 63, wv = threadIdx.x >> 6;
  int wy = wv >> 1, wx = wv & 1;
  int l15 = lane & 15, q4 = lane >> 4;
  int lr = lane >> 3, lchunk = lane & 7;
  __shared__ h16 pool[128 * 136];
  h16* Al = pool;
  h16* Bl = pool + 128 * 64;
#pragma unroll
  for (int inst = 0; inst < 4; inst++) {
    int rbase = 32 * wv + 8 * inst;
    int row = rbase + lr;
    int sc_ = (lchunk ^ (row & 7)) * 8;
    glds16(A + (size_t)(rt * 128 + row) * DH + sc_, Al + rbase * 64);
    glds16(Bv + (size_t)(jt * 128 + row) * DH + sc_, Bl + rbase * 64);
  }
  __syncthreads();
  f32x4 acc[4][4] = {};
#pragma unroll
  for (int ks = 0; ks < 2; ks++) {
    int co = 32 * ks + 8 * q4;
    h16x8 af[4], bfv[4];
#pragma unroll
    for (int i = 0; i < 4; i++) {
      int row = 64 * wy + 16 * i + l15;
      af[i] = *(const h16x8*)((const char*)Al + ((row * 128 + co * 2) ^ ((row & 7) << 4)));
    }
#pragma unroll
    for (int j = 0; j < 4; j++) {
      int row = 64 * wx + 16 * j + l15;
      bfv[j] = *(const h16x8*)((const char*)Bl + ((row * 128 + co * 2) ^ ((row & 7) << 4)));
    }
#pragma unroll
    for (int i = 0; i < 4; i++)
#pragma unroll
      for (int j = 0; j < 4; j++) acc[i][j] = mfma16(af[i], bfv[j], acc[i][j]);
  }
  __syncthreads();
  h16 (*Clds)[136] = (h16(*)[136])pool;
#pragma unroll
  for (int i = 0; i < 4; i++)
#pragma unroll
    for (int j = 0; j < 4; j++)
#pragma unroll
      for (int r = 0; r < 4; r++) {
        int rloc = 64 * wy + 16 * i + q4 * 4 + r;
        int cloc = 64 * wx + 16 * j + l15;
        int gr = rt * 128 + rloc;
        int gj = jt * 128 + cloc;
        float v = acc[i][j][r];
        float o;
        if (!is_sig) o = (gj <= gr) ? v : 0.f;
        else         o = (gj > gr) ? 1.f / (1.f + __expf(-v)) : 0.f;
        Clds[rloc][cloc] = (h16)o;
      }
  __syncthreads();
  int t = threadIdx.x;
  int rloc = t >> 1, half = t & 1;
  h16* dst = out + (size_t)(rt * 128 + rloc) * NN + jt * 128 + 64 * half;
#pragma unroll
  for (int e = 0; e < 8; e++)
    *(h16x8*)(dst + 8 * e) = *(const h16x8*)&Clds[rloc][64 * half + 8 * e];
}

// ---------------- scores + softmax partials + fused PV ----------------
// s = Qc_s.Kc^T - silu(term @ sig^T), causal mask. Per (It,Kt) block:
// emits pmax/psum per row and partial O_t = exp(s - pmax_t) @ Vc  (f32 [128][64]).
__global__ __launch_bounds__(256) void k_scores(const h16* __restrict__ qkv,
                                                const h16* __restrict__ term, const h16* __restrict__ sig,
                                                const h16* __restrict__ vcT,
                                                float* __restrict__ Ot,
                                                float* __restrict__ pmax, float* __restrict__ psum, int bh0) {
  __shared__ h16 pool[128 * 136];  // loop: Al+Bl (32KB); epilogue: Clds[128][136] (raw s, then P)
  __shared__ float rowM[128];
  h16* Al = pool;
  h16* Bl = pool + 128 * 64;
  int nwg = gridDim.x;
  int q = nwg >> 3, rmd = nwg & 7;
  int xcd = blockIdx.x & 7, idx = blockIdx.x >> 3;
  int wg = (xcd < rmd) ? xcd * (q + 1) + idx : rmd * (q + 1) + (xcd - rmd) * q + idx;
  int lz = wg / 136, r = wg % 136;
  int It = 15, base = 0;               // descending: longest K-loops first
  while (r - base >= It + 1) { base += It + 1; --It; }
  int Kt = r - base;                   // Kt <= It
  int bh = bh0 + lz;
  const h16* Ab = term + (size_t)lz * NN * NN + (size_t)(It * 128) * NN;
  const h16* Bb = sig + (size_t)lz * NN * NN + (size_t)(Kt * 128) * NN;
  int i0 = It * 128, k0 = Kt * 128;
  int lane = threadIdx.x & 63, wv = threadIdx.x >> 6;
  int wy = wv >> 1, wx = wv & 1;
  int l15 = lane & 15, q4 = lane >> 4;
  int lr = lane >> 3, lchunk = lane & 7;
  f32x4 acc[4][4] = {};
  for (int js = k0; js < i0 + 128; js += 64) {
#pragma unroll
    for (int inst = 0; inst < 4; inst++) {
      int rbase = 32 * wv + 8 * inst;
      int row = rbase + lr;
      int sc_ = (lchunk ^ (row & 7)) * 8;
      glds16(Ab + (size_t)row * NN + js + sc_, Al + rbase * 64);
      glds16(Bb + (size_t)row * NN + js + sc_, Bl + rbase * 64);
    }
    __syncthreads();
#pragma unroll
    for (int ks = 0; ks < 2; ks++) {
      int co = 32 * ks + 8 * q4;
      h16x8 af[4], bfv[4];
#pragma unroll
      for (int i = 0; i < 4; i++) {
        int row = 64 * wy + 16 * i + l15;
        af[i] = *(const h16x8*)((const char*)Al + ((row * 128 + co * 2) ^ ((row & 7) << 4)));
      }
#pragma unroll
      for (int j = 0; j < 4; j++) {
        int row = 64 * wx + 16 * j + l15;
        bfv[j] = *(const h16x8*)((const char*)Bl + ((row * 128 + co * 2) ^ ((row & 7) << 4)));
      }
#pragma unroll
      for (int i = 0; i < 4; i++)
#pragma unroll
        for (int j = 0; j < 4; j++) acc[i][j] = mfma16(af[i], bfv[j], acc[i][j]);
    }
    __syncthreads();
  }
  // acc = -silu(S_u)
#pragma unroll
  for (int i = 0; i < 4; i++)
#pragma unroll
    for (int j = 0; j < 4; j++)
#pragma unroll
      for (int rr = 0; rr < 4; rr++) {
        float xv = acc[i][j][rr];
        acc[i][j][rr] = -xv / (1.f + __expf(-xv));
      }
  // acc += Qc_s . Kc^T
  const h16* Q  = qkv + ((size_t)3 * BH + bh) * NN * DH;
  const h16* Kc = qkv + ((size_t)4 * BH + bh) * NN * DH;
#pragma unroll
  for (int d2 = 0; d2 < 2; d2++) {
    int kb = 32 * d2 + 8 * q4;
    h16x8 af[4], bfv[4];
#pragma unroll
    for (int i = 0; i < 4; i++)
      af[i] = *(const h16x8*)(Q + (size_t)(i0 + 64 * wy + 16 * i + l15) * DH + kb);
#pragma unroll
    for (int j = 0; j < 4; j++)
      bfv[j] = *(const h16x8*)(Kc + (size_t)(k0 + 64 * wx + 16 * j + l15) * DH + kb);
#pragma unroll
    for (int i = 0; i < 4; i++)
#pragma unroll
      for (int j = 0; j < 4; j++) acc[i][j] = mfma16(af[i], bfv[j], acc[i][j]);
  }
  // --- stage masked raw scores in LDS ---
  h16 (*Clds)[136] = (h16(*)[136])pool;
#pragma unroll
  for (int i = 0; i < 4; i++)
#pragma unroll
    for (int j = 0; j < 4; j++)
#pragma unroll
      for (int rr = 0; rr < 4; rr++) {
        int rloc = 64 * wy + 16 * i + q4 * 4 + rr;
        int cloc = 64 * wx + 16 * j + l15;
        float v = (k0 + cloc <= i0 + rloc) ? acc[i][j][rr] : -__builtin_inff();
        Clds[rloc][cloc] = (h16)v;
      }
  __syncthreads();
  // --- per-row tile max / sumexp partials ---
  int t = threadIdx.x;
  {
    int rloc = t >> 1, half = t & 1;
    float mx = -1e30f, ls = 0.f;
#pragma unroll
    for (int e = 0; e < 8; e++) {
      h16x8 v8 = *(const h16x8*)&Clds[rloc][64 * half + 8 * e];
      float cm = mx;
#pragma unroll
      for (int qe = 0; qe < 8; qe++) cm = fmaxf(cm, (float)v8[qe]);
      ls *= __expf(mx - cm);
#pragma unroll
      for (int qe = 0; qe < 8; qe++) ls += __expf((float)v8[qe] - cm);
      mx = cm;
    }
    float om = __shfl_xor(mx, 1), ol = __shfl_xor(ls, 1);
    float M = fmaxf(mx, om);
    float L = ls * __expf(mx - M) + ol * __expf(om - M);
    if (half == 0) {
      size_t pi = ((size_t)lz * 16 + Kt) * NN + i0 + rloc;
      pmax[pi] = M;
      psum[pi] = L;
      rowM[rloc] = M;
    }
  }
  __syncthreads();
  // --- exp pass: Clds <- P = exp(s - M_tile) ---
  {
    int rloc = t >> 1, half = t & 1;
    float M = rowM[rloc];
#pragma unroll
    for (int e = 0; e < 8; e++) {
      h16x8 v8 = *(const h16x8*)&Clds[rloc][64 * half + 8 * e];
      h16x8 o8;
#pragma unroll
      for (int qe = 0; qe < 8; qe++) o8[qe] = (h16)__expf((float)v8[qe] - M);
      *(h16x8*)&Clds[rloc][64 * half + 8 * e] = o8;
    }
  }
  __syncthreads();
  // --- fused PV: O_t = P @ Vc[Kt-tile]  (each wave: 64 rows x 32 d) ---
  const h16* VT = vcT + (size_t)bh * DH * NN;  // [d][n]
  f32x4 acc2[4][2] = {};
#pragma unroll
  for (int ks = 0; ks < 4; ks++) {
    int co = 32 * ks + 8 * q4;
    h16x8 bf2[2];
#pragma unroll
    for (int n = 0; n < 2; n++)
      bf2[n] = *(const h16x8*)(VT + (size_t)(32 * wx + 16 * n + l15) * NN + k0 + co);
#pragma unroll
    for (int m = 0; m < 4; m++) {
      h16x8 af2 = *(const h16x8*)&Clds[64 * wy + 16 * m + l15][co];
#pragma unroll
      for (int n = 0; n < 2; n++) acc2[m][n] = mfma16(af2, bf2[n], acc2[m][n]);
    }
  }
  float* ob = Ot + ((size_t)lz * 136 + (size_t)(It * (It + 1) / 2) + Kt) * (128 * 64);
#pragma unroll
  for (int m = 0; m < 4; m++)
#pragma unroll
    for (int n = 0; n < 2; n++)
#pragma unroll
      for (int rr = 0; rr < 4; rr++) {
        int row = 64 * wy + 16 * m + 4 * q4 + rr;
        int col = 32 * wx + 16 * n + l15;
        ob[row * 64 + col] = acc2[m][n][rr];
      }
}

// ---------------- merge partial O tiles -> attn ----------------
__global__ __launch_bounds__(256) void k_pvm(const float* __restrict__ Ot,
                                             const float* __restrict__ pmax, const float* __restrict__ psum,
                                             h16* __restrict__ attn, int bh0) {
  int It = blockIdx.x, lz = blockIdx.y, bh = bh0 + lz;
  int t = threadIdx.x;
  int rloc = t >> 1, dh = (t & 1) * 32;
  int i = It * 128 + rloc;
  int ntk = It + 1;
  int triIt = It * (It + 1) / 2;
  const float* pm = pmax + (size_t)lz * 16 * NN + i;
  const float* pl = psum + (size_t)lz * 16 * NN + i;
  float M = -1e30f;
  for (int k = 0; k < ntk; k++) M = fmaxf(M, pm[(size_t)k * NN]);
  float L = 0.f;
  for (int k = 0; k < ntk; k++) L += pl[(size_t)k * NN] * __expf(pm[(size_t)k * NN] - M);
  float invL = 1.f / L;
  f32x4 acc[8] = {};
  for (int k = 0; k < ntk; k++) {
    float s = __expf(pm[(size_t)k * NN] - M);
    const float* ob = Ot + ((size_t)lz * 136 + triIt + k) * (128 * 64) + (size_t)rloc * 64 + dh;
#pragma unroll
    for (int e = 0; e < 8; e++) {
      f32x4 v = *(const f32x4*)(ob + 4 * e);
      acc[e] += v * s;
    }
  }
  int hh = bh & 7, b = bh >> 3;
  h16* dst = attn + ((size_t)b * NN + i) * DIM + hh * DH + dh;
#pragma unroll
  for (int g = 0; g < 4; g++) {
    h16x8 o;
#pragma unroll
    for (int qe = 0; qe < 8; qe++) {
      int ii = g * 8 + qe;
      o[qe] = (h16)(acc[ii >> 2][ii & 3] * invL);
    }
    *(h16x8*)(dst + 8 * g) = o;
  }
}

// ---------------- output projection (fp32 out) ----------------
__global__ __launch_bounds__(256) void k_outproj(const h16* __restrict__ attn, const h16* __restrict__ Wt,
                                                 float* __restrict__ out) {
  int m0 = blockIdx.x * 64, o0 = blockIdx.y * 64;
  int lane = threadIdx.x & 63, wv = threadIdx.x >> 6;
  int kb = 8 * (lane >> 4);
  f32x4 acc[4] = {};
  const h16* ap = attn + (size_t)(m0 + 16 * wv + (lane & 15)) * DIM + kb;
  const h16* bp = Wt + (size_t)(o0 + (lane & 15)) * DIM + kb;
  for (int k0 = 0; k0 < DIM; k0 += 32) {
    h16x8 af = *(const h16x8*)(ap + k0);
#pragma unroll
    for (int t = 0; t < 4; t++) {
      h16x8 bfv = *(const h16x8*)(bp + (size_t)(16 * t) * DIM + k0);
      acc[t] = mfma16(af, bfv, acc[t]);
    }
  }
  int ri = m0 + 16 * wv + (lane >> 4) * 4;
  int c0 = o0 + (lane & 15);
#pragma unroll
  for (int t = 0; t < 4; t++)
#pragma unroll
    for (int r = 0; r < 4; r++) out[(size_t)(ri + r) * DIM + c0 + 16 * t] = acc[t][r];
}

// ---------------- launch ----------------

extern "C" void kernel_launch(void* const* d_in, const int* in_sizes, int n_in,
                              void* d_out, int out_size, void* d_ws, size_t ws_size,
                              hipStream_t stream) {
  const float* x = (const float*)d_in[0];
  WPtrs wp;
  for (int i = 0; i < 7; i++) wp.w[i] = (const float*)d_in[1 + i];

  char* p = (char*)d_ws;
  auto alloc = [&](size_t bytes) {
    void* r = (void*)p;
    p += (bytes + 255) & ~(size_t)255;
    return r;
  };
  h16* xh   = (h16*)alloc((size_t)4096 * DIM * 2);            // 4 MB
  h16* wt   = (h16*)alloc((size_t)7 * DIM * DIM * 2);         // 3.5 MB
  h16* qkv  = (h16*)alloc((size_t)6 * BH * NN * DH * 2);      // 24 MB
  h16* vcT  = (h16*)alloc((size_t)BH * DH * NN * 2);          // 4 MB
  h16* attn = (h16*)alloc((size_t)4096 * DIM * 2);            // 4 MB
  size_t used = (size_t)(p - (char*)d_ws);
  size_t per_bh = (size_t)NN * NN * 2;                        // 8 MB (term/sig each)
  size_t ot_bh  = (size_t)136 * 128 * 64 * 4;                 // 4.46 MB partial-O per bh
  size_t pp_bh  = (size_t)16 * NN * 4;                        // 128 KB partials per bh each
  size_t avail = ws_size > used ? ws_size - used : 0;
  int CH = 8;  // chunk working set ~194 MB -> L3-resident
  while (CH > 1 && (size_t)CH * (per_bh * 2 + ot_bh + pp_bh * 2) > avail) CH >>= 1;
  h16* term   = (h16*)alloc((size_t)CH * per_bh);
  h16* sig    = (h16*)alloc((size_t)CH * per_bh);
  float* Ot   = (float*)alloc((size_t)CH * ot_bh);
  float* pmax = (float*)alloc((size_t)CH * pp_bh);
  float* psum = (float*)alloc((size_t)CH * pp_bh);

  k_pack_x<<<dim3(2048), dim3(256), 0, stream>>>(x, xh);
  k_pack_w<<<dim3(8, 8, 7), dim3(256), 0, stream>>>(wp, wt);
  k_proj<<<dim3(32, 24), dim3(256), 0, stream>>>(xh, wt, qkv, vcT);

  for (int c0 = 0; c0 < BH; c0 += CH) {
    k_termsig<<<dim3(152, 2, CH), dim3(256), 0, stream>>>(qkv, term, sig, c0);
    k_scores<<<dim3(136 * CH), dim3(256), 0, stream>>>(qkv, term, sig, vcT, Ot, pmax, psum, c0);
    k_pvm<<<dim3(16, CH), dim3(256), 0, stream>>>(Ot, pmax, psum, attn, c0);
  }

  k_outproj<<<dim3(64, 8), dim3(256), 0, stream>>>(attn, wt + (size_t)6 * DIM * DIM, (float*)d_out);
}